// Round 5
// baseline (693.223 us; speedup 1.0000x reference)
//
#include <hip/hip_runtime.h>
#include <hip/hip_bf16.h>

// CCAttention pipeline on MI355X. fp32 in/out, bf16 MFMA internal, NHWC.
// B=2, CIN=2048, CINT=512, CQK=64, H=W=96, S=9216, NG=32.
// R6: 128x64 tiles for conv1/qkv gemm_async (grid 1152/1440). KEPT.
// R7: conv3 at 128x128; gn_stats 256-block linear+atomic. KEPT.
// R9 (agg staging remap) REVERTED: qkv is L2/L3-resident so line-overfetch
// was free; the remap paid 4-way LDS write conflicts for nothing (+15us).
// R10: 2-phase double-buffered pipeline in gemm_async + conv3 (T3 minimum):
// stage(next tile -> buf^1); s_waitcnt vmcnt(6|8) [counted -- waits ONLY the
// previous tile's loads]; raw s_barrier; MFMA on buf; raw s_barrier. Removes
// the vmcnt(0) full-drain __syncthreads emitted each K-step (the ~60% stall
// at 2.25 blocks/CU). LDS: gemm 48KB, conv3 64KB (2 blocks/CU).

typedef __bf16 bf8_t __attribute__((ext_vector_type(8)));
typedef float f32x4 __attribute__((ext_vector_type(4)));

union I4B8 { int4 i; bf8_t b; };

typedef const __attribute__((address_space(1))) void as1_cvoid;
typedef __attribute__((address_space(3))) void as3_void;
__device__ __forceinline__ void gload16(const void* g, void* l) {
  __builtin_amdgcn_global_load_lds((as1_cvoid*)g, (as3_void*)l, 16, 0, 0);
}
__device__ __forceinline__ int rot8(int c, int key) { return (c + key) & 7; }

// ---------------------------------------------------------------- weight prep
__global__ __launch_bounds__(256) void cast_rot_k(const float* s, __bf16* d, int K8, int total8) {
  int idx = blockIdx.x * 256 + threadIdx.x;
  if (idx >= total8) return;
  int c8 = idx % K8, n = idx / K8;
  int pos = rot8(c8 & 7, n & 7);
  const float* sp = s + ((long long)n * K8 + c8) * 8;
  float4 a = *(const float4*)sp, b = *(const float4*)(sp + 4);
  I4B8 u;
  u.b[0] = (__bf16)a.x; u.b[1] = (__bf16)a.y; u.b[2] = (__bf16)a.z; u.b[3] = (__bf16)a.w;
  u.b[4] = (__bf16)b.x; u.b[5] = (__bf16)b.y; u.b[6] = (__bf16)b.z; u.b[7] = (__bf16)b.w;
  *(int4*)(d + ((long long)n * K8 + (c8 & ~7) + pos) * 8) = u.i;
}

__global__ __launch_bounds__(256) void wqkv_rot_k(const float* qw, const float* kw, const float* vw, __bf16* d) {
  int idx = blockIdx.x * 256 + threadIdx.x;  // 640*64
  if (idx >= 640 * 64) return;
  int c8 = idx & 63, n = idx >> 6;
  const float* src = (n < 64) ? qw + (long long)n * 512
                   : (n < 128) ? kw + (long long)(n - 64) * 512
                               : vw + (long long)(n - 128) * 512;
  int pos = rot8(c8 & 7, n & 7);
  const float* sp = src + c8 * 8;
  float4 a = *(const float4*)sp, b = *(const float4*)(sp + 4);
  I4B8 u;
  u.b[0] = (__bf16)a.x; u.b[1] = (__bf16)a.y; u.b[2] = (__bf16)a.z; u.b[3] = (__bf16)a.w;
  u.b[4] = (__bf16)b.x; u.b[5] = (__bf16)b.y; u.b[6] = (__bf16)b.z; u.b[7] = (__bf16)b.w;
  *(int4*)(d + ((long long)n * 64 + (c8 & ~7) + pos) * 8) = u.i;
}

// also zeroes the 128-float stats accumulator (consumed much later by gn)
__global__ __launch_bounds__(256) void fuse_bias_k(const float* qb, const float* kb, const float* vb,
                                                   float* d, float* stats) {
  int i = blockIdx.x * 256 + threadIdx.x;
  if (i < 128) stats[i] = 0.f;
  if (i >= 640) return;
  d[i] = (i < 64) ? qb[i] : (i < 128) ? kb[i - 64] : vb[i - 128];
}

// conv3 weights -> wr[o][dydx*512+c] rotated by o&7; coalesced via LDS.
__global__ __launch_bounds__(256) void reorder_w_k(const float* w, __bf16* wr) {
  __shared__ float ls[4608];
  int o = blockIdx.x;
  int t = threadIdx.x;
  const float* base = w + (long long)o * 4608;
#pragma unroll
  for (int i = 0; i < 18; i++) ls[t + i * 256] = base[t + i * 256];
  __syncthreads();
#pragma unroll
  for (int i = 0; i < 3; i++) {
    int q = t + i * 256;
    if (q >= 576) break;
    int k0 = q * 8;
    int dydx = k0 / 512, c0 = k0 & 511;
    I4B8 u;
#pragma unroll
    for (int j = 0; j < 8; j++) u.b[j] = (__bf16)ls[(c0 + j) * 9 + dydx];
    int pos = rot8((k0 >> 3) & 7, o & 7);
    *(int4*)(wr + (long long)o * 4608 + (k0 & ~63) + pos * 8) = u.i;
  }
}

// x f32 NCHW -> xt bf16 NHWC, rotated by pixel&7.
__global__ __launch_bounds__(256) void transpose_x_k(const float* x, __bf16* xt) {
  __shared__ __bf16 l[64 * 66];
  int c0 = blockIdx.x * 64, s0 = blockIdx.y * 64, b = blockIdx.z;
  int t = threadIdx.x;
#pragma unroll
  for (int i = 0; i < 2; i++) {
    int slot = t + i * 256;
    int cl = slot >> 3, sch = slot & 7;
    const float* src = x + ((long long)(b * 2048 + c0 + cl)) * 9216 + s0 + sch * 8;
    float4 a = *(const float4*)src, bb = *(const float4*)(src + 4);
    __bf16* dst = &l[cl * 66 + sch * 8];
    dst[0] = (__bf16)a.x; dst[1] = (__bf16)a.y; dst[2] = (__bf16)a.z; dst[3] = (__bf16)a.w;
    dst[4] = (__bf16)bb.x; dst[5] = (__bf16)bb.y; dst[6] = (__bf16)bb.z; dst[7] = (__bf16)bb.w;
  }
  __syncthreads();
#pragma unroll
  for (int i = 0; i < 2; i++) {
    int slot = t + i * 256;
    int sl = slot >> 3, cch = slot & 7;
    I4B8 u;
#pragma unroll
    for (int j = 0; j < 8; j++) u.b[j] = l[(cch * 8 + j) * 66 + sl];
    *(int4*)(xt + ((long long)(b * 9216 + s0 + sl)) * 2048 + c0 + rot8(cch, sl & 7) * 8) = u.i;
  }
}

// zero the padb border pixels (interior is written by agg2 it=1)
__global__ __launch_bounds__(256) void border0_k(__bf16* padb) {
  int idx = blockIdx.x * 256 + threadIdx.x;  // 776 border pixels * 64 int4
  if (idx >= 776 * 64) return;
  int ch = idx & 63, bi = idx >> 6;
  int b = bi / 388, r = bi % 388;
  int hh, ww;
  if (r < 98) { hh = 0; ww = r; }
  else if (r < 196) { hh = 97; ww = r - 98; }
  else if (r < 292) { hh = r - 196 + 1; ww = 0; }
  else { hh = r - 292 + 1; ww = 97; }
  *(int4*)(padb + ((long long)(b * 9604 + hh * 98 + ww)) * 512 + ch * 8) = make_int4(0, 0, 0, 0);
}

// ---------------------------------------------------------------- async GEMM
// 128(M)x64(N) tiles, 4 waves in 2x2, wave tile 64x32, acc[4][2].
// R10: 2-phase dbuf; counted vmcnt(6); raw barriers.
struct GemmAP {
  const __bf16 *A, *B;
  __bf16* C;
  const float* bias;
  long long sAr, sBr, sCr;
  int K, ntn;
};

template <int CROT>
__global__ __launch_bounds__(256) void gemm_async_k(GemmAP p) {
  __shared__ __attribute__((aligned(16))) __bf16 lA[2][128 * 64];
  __shared__ __attribute__((aligned(16))) __bf16 lB[2][64 * 64];
  const int t = threadIdx.x;
  const int id = blockIdx.x;
  const int per8 = gridDim.x >> 3;
  const int lin = (id & 7) * per8 + (id >> 3);
  const int m0 = (lin / p.ntn) * 128, n0 = (lin % p.ntn) * 64;
  const int lane = t & 63, wave = t >> 6;
  const int wm = (wave >> 1) * 64, wn = (wave & 1) * 32;
  const int l15 = lane & 15, l4 = lane >> 4;
  const int srow = (lane >> 3), schunk = (lane & 7) * 8;
  const int rbA = wave * 32, rbB = wave * 16;
  f32x4 acc[4][2];
#pragma unroll
  for (int i = 0; i < 4; i++)
#pragma unroll
    for (int j = 0; j < 2; j++) acc[i][j] = f32x4{0.f, 0.f, 0.f, 0.f};

  auto stage = [&](int bu, int kb) {
#pragma unroll
    for (int i = 0; i < 4; i++) {
      int row = rbA + i * 8;
      gload16(p.A + (long long)(m0 + row + srow) * p.sAr + kb + schunk, &lA[bu][row * 64]);
    }
#pragma unroll
    for (int i = 0; i < 2; i++) {
      int row = rbB + i * 8;
      gload16(p.B + (long long)(n0 + row + srow) * p.sBr + kb + schunk, &lB[bu][row * 64]);
    }
  };

  stage(0, 0);
  int bu = 0;
  for (int kb = 0; kb < p.K; kb += 64) {
    if (kb + 64 < p.K) {
      stage(bu ^ 1, kb + 64);
      asm volatile("s_waitcnt vmcnt(6)" ::: "memory");
    } else {
      asm volatile("s_waitcnt vmcnt(0)" ::: "memory");
    }
    __builtin_amdgcn_s_barrier();
#pragma unroll
    for (int kk = 0; kk < 2; kk++) {
      bf8_t af[4], bfr[2];
      int cch = kk * 4 + l4;
#pragma unroll
      for (int mt = 0; mt < 4; mt++) {
        int r = wm + mt * 16 + l15;
        af[mt] = *(bf8_t*)&lA[bu][r * 64 + (rot8(cch, r & 7) << 3)];
      }
#pragma unroll
      for (int nt = 0; nt < 2; nt++) {
        int r = wn + nt * 16 + l15;
        bfr[nt] = *(bf8_t*)&lB[bu][r * 64 + (rot8(cch, r & 7) << 3)];
      }
#pragma unroll
      for (int mt = 0; mt < 4; mt++)
#pragma unroll
        for (int nt = 0; nt < 2; nt++)
          acc[mt][nt] = __builtin_amdgcn_mfma_f32_16x16x32_bf16(af[mt], bfr[nt], acc[mt][nt], 0, 0, 0);
    }
    if (kb + 64 < p.K) __builtin_amdgcn_s_barrier();
    bu ^= 1;
  }
#pragma unroll
  for (int nt = 0; nt < 2; nt++) {
    int col = n0 + wn + nt * 16 + l15;
    float bv = p.bias[col];
#pragma unroll
    for (int mt = 0; mt < 4; mt++) {
      int row0 = m0 + wm + mt * 16 + (l4 << 2);
#pragma unroll
      for (int r = 0; r < 4; r++) {
        int row = row0 + r;
        int pc = CROT ? (col & ~63) + (rot8((col >> 3) & 7, row & 7) << 3) + (col & 7) : col;
        p.C[(long long)row * p.sCr + pc] = (__bf16)(acc[mt][nt][r] + bv);
      }
    }
  }
}

// ---------------------------------------------------------------- agg GEMM
// Batched 96(M)x512(N)x128(Kpad) GEMM. A (a_h/a_w): rows pre-rotated (key
// row&7), padded K=128, batch stride 96*128 -> async staging. B: V section
// of qkv, transposed-in-LDS (k rows, guard k<96 -> zeros).  [R2 staging]
// MODE 0: C=acc (tmp1). MODE 1: C[rot]=g*(tmp+acc)+res. MODE 2: same but
// store into padb at (h+1,w+1) with key (w+1)&7.
struct AggP {
  const __bf16 *A, *B;  // B = qkv + 128 (V columns)
  __bf16* C;
  const __bf16 *tmp, *res;
  const float* gma;
  long long bB1, bB2, sBr;
  long long cB1, cB2, sCr;
};

template <int MODE>
__global__ __launch_bounds__(256) void agg_k(AggP p) {
  __shared__ __attribute__((aligned(16))) __bf16 lA[128 * 64];
  __shared__ __attribute__((aligned(16))) __bf16 lB[128 * 64];
  const int t = threadIdx.x;
  const int z = blockIdx.z;
  const int z1 = z / 96, z2 = z % 96;
  const __bf16* A = p.A + (long long)z * (96 * 128);
  const __bf16* B = p.B + (long long)z1 * p.bB1 + (long long)z2 * p.bB2;
  const int n0 = blockIdx.x * 128;
  const int lane = t & 63, wave = t >> 6;
  const int wm = (wave >> 1) * 64, wn = (wave & 1) * 64;
  const int l15 = lane & 15, l4 = lane >> 4;
  const int srow = lane >> 3, schunk = (lane & 7) * 8;
  f32x4 acc[4][4];
#pragma unroll
  for (int i = 0; i < 4; i++)
#pragma unroll
    for (int j = 0; j < 4; j++) acc[i][j] = f32x4{0.f, 0.f, 0.f, 0.f};

#pragma unroll
  for (int kb = 0; kb < 128; kb += 64) {
    const int rb = wave * 32;
#pragma unroll
    for (int i = 0; i < 4; i++) {
      int row = rb + i * 8;
      gload16(A + (long long)(row + srow) * 128 + kb + schunk, &lA[row * 64]);
    }
#pragma unroll
    for (int i = 0; i < 4; i++) {
      int slot = t + i * 256;
      int kl = slot & 63, cch = slot >> 6;
      int gk = kb + kl;
      I4B8 u;
      u.i = make_int4(0, 0, 0, 0);
      if (gk < 96) u.i = *(const int4*)(B + (long long)gk * p.sBr + n0 + cch * 8);
#pragma unroll
      for (int j = 0; j < 8; j++) {
        int n = cch * 8 + j;
        lB[n * 64 + (rot8(kl >> 3, n & 7) << 3) + (kl & 7)] = u.b[j];
      }
    }
    __syncthreads();
#pragma unroll
    for (int kk = 0; kk < 2; kk++) {
      bf8_t af[4], bfr[4];
      int cch = kk * 4 + l4;
#pragma unroll
      for (int mt = 0; mt < 4; mt++) {
        int r = wm + mt * 16 + l15;
        af[mt] = *(bf8_t*)&lA[r * 64 + (rot8(cch, r & 7) << 3)];
      }
#pragma unroll
      for (int nt = 0; nt < 4; nt++) {
        int r = wn + nt * 16 + l15;
        bfr[nt] = *(bf8_t*)&lB[r * 64 + (rot8(cch, r & 7) << 3)];
      }
#pragma unroll
      for (int mt = 0; mt < 4; mt++)
#pragma unroll
        for (int nt = 0; nt < 4; nt++)
          acc[mt][nt] = __builtin_amdgcn_mfma_f32_16x16x32_bf16(af[mt], bfr[nt], acc[mt][nt], 0, 0, 0);
    }
    __syncthreads();
  }
  long long cbase = (long long)z1 * p.cB1 + (long long)z2 * p.cB2;
  float g = MODE ? *p.gma : 0.f;
#pragma unroll
  for (int nt = 0; nt < 4; nt++) {
    int col = n0 + wn + nt * 16 + l15;
#pragma unroll
    for (int mt = 0; mt < 4; mt++) {
      int row0 = wm + mt * 16 + (l4 << 2);
#pragma unroll
      for (int r = 0; r < 4; r++) {
        int row = row0 + r;
        if (row >= 96) continue;
        long long offL = cbase + (long long)row * p.sCr + col;
        float v = acc[mt][nt][r];
        if (MODE == 0) {
          p.C[offL] = (__bf16)v;
        } else {
          int rc = (col & ~63) + (rot8((col >> 3) & 7, row & 7) << 3) + (col & 7);
          long long offP = cbase + (long long)row * p.sCr + rc;
          v = g * ((float)p.tmp[offL] + v) + (float)p.res[offP];
          if (MODE == 1) {
            p.C[offP] = (__bf16)v;
          } else {
            int pc = (col & ~63) + (rot8((col >> 3) & 7, (row + 1) & 7) << 3) + (col & 7);
            long long pidx = (long long)z1 * 9604 + (long long)(z2 + 1) * 98 + (row + 1);
            p.C[pidx * 512 + pc] = (__bf16)v;
          }
        }
      }
    }
  }
}

// ---------------------------------------------------------------- scores
// mode 0 (b,w): E[h][i] (diag -inf) -> attnfH[b*96+w][h*96+i]
// mode 1 (b,h): E[w][j]             -> attnfW[b*96+h][w*96+j]
__global__ __launch_bounds__(384) void cc_scores_k(const __bf16* qkv, float* attnfH, float* attnfW) {
  __shared__ __attribute__((aligned(16))) __bf16 Qs[96 * 64];
  __shared__ __attribute__((aligned(16))) __bf16 Ks[96 * 64];
  int bfi = blockIdx.x;
  int b = bfi / 96, f = bfi % 96;
  int mode = blockIdx.y;
  long long base = (mode == 0) ? ((long long)(b * 9216 + f)) * 640 : ((long long)(b * 9216 + f * 96)) * 640;
  long long rstr = (mode == 0) ? 96 * 640 : 640;
  int t = threadIdx.x;
#pragma unroll
  for (int i = 0; i < 2; i++) {
    int slot = t + i * 384;
    int r = slot >> 3, c = slot & 7;
    int sw = rot8(c, r & 7) << 3;
    *(int4*)&Qs[r * 64 + sw] = *(const int4*)(qkv + base + (long long)r * rstr + c * 8);
    *(int4*)&Ks[r * 64 + sw] = *(const int4*)(qkv + base + (long long)r * rstr + 64 + c * 8);
  }
  __syncthreads();
  int lane = t & 63, wave = t >> 6;
  int l15 = lane & 15, l4 = lane >> 4;
  f32x4 acc[6];
#pragma unroll
  for (int i = 0; i < 6; i++) acc[i] = f32x4{0.f, 0.f, 0.f, 0.f};
#pragma unroll
  for (int kk = 0; kk < 2; kk++) {
    int ar = wave * 16 + l15;
    int cch = kk * 4 + l4;
    bf8_t af = *(bf8_t*)&Qs[ar * 64 + (rot8(cch, ar & 7) << 3)];
#pragma unroll
    for (int nt = 0; nt < 6; nt++) {
      int br = nt * 16 + l15;
      bf8_t bfr = *(bf8_t*)&Ks[br * 64 + (rot8(cch, br & 7) << 3)];
      acc[nt] = __builtin_amdgcn_mfma_f32_16x16x32_bf16(af, bfr, acc[nt], 0, 0, 0);
    }
  }
  float* dst = (mode == 0 ? attnfH : attnfW) + (long long)bfi * 9216;
#pragma unroll
  for (int nt = 0; nt < 6; nt++) {
#pragma unroll
    for (int r = 0; r < 4; r++) {
      int m = wave * 16 + (l4 << 2) + r;
      int n = nt * 16 + l15;
      float v = acc[nt][r];
      if (mode == 0 && n == m) v = -__builtin_inff();
      dst[m * 96 + n] = v;
    }
  }
}

// softmax over concat[e_h, e_w] (192), writes padded+rotated a_h/a_w rows.
__global__ __launch_bounds__(256) void cc_softmax_k(const float* attnfH, const float* attnfW,
                                                    __bf16* a_h, __bf16* a_w) {
  int wave = threadIdx.x >> 6, lane = threadIdx.x & 63;
  int pix = blockIdx.x * 4 + wave;
  int b = pix / 9216, hw = pix % 9216;
  int h = hw / 96, w2 = hw % 96;
  const float* ehb = attnfH + ((long long)(b * 96 + w2)) * 9216 + h * 96;
  const float* ewb = attnfW + ((long long)(b * 96 + h)) * 9216 + w2 * 96;
  float x0 = ehb[lane];
  float x1 = lane < 32 ? ehb[64 + lane] : -__builtin_inff();
  float x2 = ewb[lane];
  float x3 = lane < 32 ? ewb[64 + lane] : -__builtin_inff();
  float m = fmaxf(fmaxf(x0, x1), fmaxf(x2, x3));
#pragma unroll
  for (int o = 32; o; o >>= 1) m = fmaxf(m, __shfl_xor(m, o));
  float e0 = __expf(x0 - m), e1 = __expf(x1 - m), e2 = __expf(x2 - m), e3 = __expf(x3 - m);
  float s = e0 + e1 + e2 + e3;
#pragma unroll
  for (int o = 32; o; o >>= 1) s += __shfl_xor(s, o);
  float inv = 1.f / s;
  // a_h row (h), key h&7 ; a_w row (w2), key w2&7
  __bf16* dh = a_h + ((long long)((b * 96 + w2) * 96 + h)) * 128;
  __bf16* dw = a_w + ((long long)((b * 96 + h) * 96 + w2)) * 128;
  int kh = h & 7, kw2 = w2 & 7;
  int k1 = lane, k2 = 64 + lane;
  int p1h = (k1 & ~63) + (rot8((k1 >> 3) & 7, kh) << 3) + (k1 & 7);
  int p2h = (k2 & ~63) + (rot8((k2 >> 3) & 7, kh) << 3) + (k2 & 7);
  int p1w = (k1 & ~63) + (rot8((k1 >> 3) & 7, kw2) << 3) + (k1 & 7);
  int p2w = (k2 & ~63) + (rot8((k2 >> 3) & 7, kw2) << 3) + (k2 & 7);
  dh[p1h] = (__bf16)(e0 * inv);
  dh[p2h] = (__bf16)(lane < 32 ? e1 * inv : 0.f);
  dw[p1w] = (__bf16)(e2 * inv);
  dw[p2w] = (__bf16)(lane < 32 ? e3 * inv : 0.f);
}

// ---------------------------------------------------------------- conv3x3
// 128x128 tiles, grid 576 (144 m-tiles x 4 n-tiles), acc[4][4].
// R10: 2-phase dbuf over linear kt=0..71; counted vmcnt(8); raw barriers.
__global__ __launch_bounds__(256) void conv3_gemm_k(const __bf16* pin, const __bf16* wr, __bf16* C) {
  __shared__ __attribute__((aligned(16))) __bf16 lA[2][128 * 64];
  __shared__ __attribute__((aligned(16))) __bf16 lB[2][128 * 64];
  const int t = threadIdx.x;
  const int id = blockIdx.x;
  const int per8 = gridDim.x >> 3;                 // 72
  const int lin = (id & 7) * per8 + (id >> 3);
  const int m0 = (lin >> 2) * 128, n0 = (lin & 3) * 128;
  const int lane = t & 63, wave = t >> 6;
  const int wm = (wave >> 1) * 64, wn = (wave & 1) * 64;
  const int l15 = lane & 15, l4 = lane >> 4;
  const int srow = lane >> 3, schunk = (lane & 7) * 8;
  const int rb = wave * 32;
  f32x4 acc[4][4];
#pragma unroll
  for (int i = 0; i < 4; i++)
#pragma unroll
    for (int j = 0; j < 4; j++) acc[i][j] = f32x4{0.f, 0.f, 0.f, 0.f};
  long long sbase[4], bbase[4];
#pragma unroll
  for (int i = 0; i < 4; i++) {
    int r = rb + i * 8 + srow;
    int m = m0 + r;
    int b = m / 9216, hw = m % 9216;
    int h = hw / 96, w2 = hw % 96;
    sbase[i] = ((long long)b * 9604 + h * 98 + w2) * 512 + schunk;
    bbase[i] = (long long)(n0 + r) * 4608 + schunk;
  }
  int w2f[4];
#pragma unroll
  for (int mt = 0; mt < 4; mt++) w2f[mt] = (m0 + wm + mt * 16 + l15) % 96;

  auto stage = [&](int bu, int kt2) {
    int tap = kt2 >> 3, sl = kt2 & 7;
    int dyq = tap / 3;
    long long aoff = (long long)(dyq * 98 + (tap - dyq * 3)) * 512;
    int c0k = sl * 64;
#pragma unroll
    for (int i = 0; i < 4; i++) {
      gload16(pin + sbase[i] + aoff + c0k, &lA[bu][(rb + i * 8) * 64]);
      gload16(wr + bbase[i] + kt2 * 64, &lB[bu][(rb + i * 8) * 64]);
    }
  };

  stage(0, 0);
  int bu = 0;
  for (int kt = 0; kt < 72; kt++) {
    if (kt < 71) {
      stage(bu ^ 1, kt + 1);
      asm volatile("s_waitcnt vmcnt(8)" ::: "memory");
    } else {
      asm volatile("s_waitcnt vmcnt(0)" ::: "memory");
    }
    __builtin_amdgcn_s_barrier();
    int tap = kt >> 3;
    int dx = tap - (tap / 3) * 3;
    int keyA[4];
#pragma unroll
    for (int mt = 0; mt < 4; mt++) keyA[mt] = (w2f[mt] + dx) & 7;
#pragma unroll
    for (int kk = 0; kk < 2; kk++) {
      bf8_t af[4], bfr[4];
      int cch = kk * 4 + l4;
#pragma unroll
      for (int mt = 0; mt < 4; mt++) {
        int r = wm + mt * 16 + l15;
        af[mt] = *(bf8_t*)&lA[bu][r * 64 + (rot8(cch, keyA[mt]) << 3)];
      }
#pragma unroll
      for (int nt = 0; nt < 4; nt++) {
        int r = wn + nt * 16 + l15;
        bfr[nt] = *(bf8_t*)&lB[bu][r * 64 + (rot8(cch, r & 7) << 3)];
      }
#pragma unroll
      for (int mt = 0; mt < 4; mt++)
#pragma unroll
        for (int nt = 0; nt < 4; nt++)
          acc[mt][nt] = __builtin_amdgcn_mfma_f32_16x16x32_bf16(af[mt], bfr[nt], acc[mt][nt], 0, 0, 0);
    }
    if (kt < 71) __builtin_amdgcn_s_barrier();
    bu ^= 1;
  }
#pragma unroll
  for (int nt = 0; nt < 4; nt++) {
    int col = n0 + wn + nt * 16 + l15;
#pragma unroll
    for (int mt = 0; mt < 4; mt++) {
      int row0 = m0 + wm + mt * 16 + (l4 << 2);
#pragma unroll
      for (int r = 0; r < 4; r++) {
        int row = row0 + r;
        C[(long long)row * 512 + col] = (__bf16)acc[mt][nt][r];
      }
    }
  }
}

// ---------------------------------------------------------------- GroupNorm
// 256 blocks (1/CU), fully linear coalesced int4 reads; atomicAdd partials.
__global__ __launch_bounds__(256) void gn_stats_k(const __bf16* z, float* stats) {
  int bi = blockIdx.x, t = threadIdx.x;
  const __bf16* base = z + (long long)bi * (72 * 512);
  int g = (t & 63) >> 1;  // channel octet (t&63)*8 -> group
  float s = 0.f, ss = 0.f;
#pragma unroll
  for (int i = 0; i < 18; i++) {
    I4B8 u;
    u.i = *(const int4*)(base + ((long long)(t + i * 256)) * 8);
#pragma unroll
    for (int j = 0; j < 8; j++) {
      float f = (float)u.b[j];
      s += f;
      ss += f * f;
    }
  }
  s += __shfl_xor(s, 1);
  ss += __shfl_xor(ss, 1);
  __shared__ float red[2][4][32];
  int wave = t >> 6, lane = t & 63;
  if (!(lane & 1)) {
    red[0][wave][g] = s;
    red[1][wave][g] = ss;
  }
  __syncthreads();
  if (t < 32) {
    float S = red[0][0][t] + red[0][1][t] + red[0][2][t] + red[0][3][t];
    float SS = red[1][0][t] + red[1][1][t] + red[1][2][t] + red[1][3][t];
    int b = bi >> 7;  // 128 blocks per batch (72*128 = 9216 px)
    atomicAdd(&stats[2 * (b * 32 + t)], S);
    atomicAdd(&stats[2 * (b * 32 + t) + 1], SS);
  }
}

__global__ __launch_bounds__(256) void gn_write_k(const __bf16* z, const float* stats,
                                                 const float* gng, const float* gnb, float* out) {
  __shared__ __bf16 l[64 * 98];
  int c0 = blockIdx.x * 64, h = blockIdx.y, b = blockIdx.z;
  int t = threadIdx.x;
#pragma unroll
  for (int i = 0; i < 3; i++) {
    int slot = t + i * 256;
    int wl = slot >> 3, cch = slot & 7;
    I4B8 u;
    u.i = *(const int4*)(z + ((long long)(b * 9216 + h * 96 + wl)) * 512 + c0 + cch * 8);
#pragma unroll
    for (int j = 0; j < 8; j++) l[(cch * 8 + j) * 98 + wl] = u.b[j];
  }
  __syncthreads();
  const float inv = 1.f / 147456.f;
#pragma unroll
  for (int i = 0; i < 3; i++) {
    int slot = t + i * 256;
    int wch = slot % 12, cl = slot / 12;
    int c = c0 + cl;
    int g = c >> 4;
    float S = stats[2 * (b * 32 + g)], SS = stats[2 * (b * 32 + g) + 1];
    float mean = S * inv;
    float rstd = rsqrtf(SS * inv - mean * mean + 1e-5f);
    float sc = rstd * gng[c];
    float sh = gnb[c] - mean * sc;
    float4 o0, o1;
    const __bf16* src = &l[cl * 98 + wch * 8];
    o0.x = (float)src[0] * sc + sh; o0.y = (float)src[1] * sc + sh;
    o0.z = (float)src[2] * sc + sh; o0.w = (float)src[3] * sc + sh;
    o1.x = (float)src[4] * sc + sh; o1.y = (float)src[5] * sc + sh;
    o1.z = (float)src[6] * sc + sh; o1.w = (float)src[7] * sc + sh;
    float* dst = out + ((long long)((b * 512 + c) * 96 + h)) * 96 + wch * 8;
    *(float4*)dst = o0;
    *(float4*)(dst + 4) = o1;
  }
}

// ---------------------------------------------------------------- launch
extern "C" void kernel_launch(void* const* d_in, const int* in_sizes, int n_in,
                              void* d_out, int out_size, void* d_ws, size_t ws_size,
                              hipStream_t stream) {
  (void)in_sizes; (void)n_in; (void)out_size;
  const float* x = (const float*)d_in[0];
  const float* conv1w = (const float*)d_in[1];
  const float* conv1b = (const float*)d_in[2];
  const float* qw = (const float*)d_in[3];
  const float* qbias = (const float*)d_in[4];
  const float* kw = (const float*)d_in[5];
  const float* kbias = (const float*)d_in[6];
  const float* vw = (const float*)d_in[7];
  const float* vbias = (const float*)d_in[8];
  const float* gma = (const float*)d_in[9];
  const float* cow = (const float*)d_in[10];
  const float* gng = (const float*)d_in[11];
  const float* gnb = (const float*)d_in[12];
  float* out = (float*)d_out;

  if (ws_size < 134876160ULL) return;

  char* w = (char*)d_ws;
  __bf16* xt     = (__bf16*)(w);                 // 75,497,472 (phase 1)
  __bf16* qkv    = (__bf16*)(w);                 // 23,592,960
  float* attnfH  = (float*)(w + 23592960);       // 7,077,888
  float* attnfW  = (float*)(w + 30670848);       // 7,077,888
  __bf16* a_h    = (__bf16*)(w + 37748736);      // 4,718,592
  __bf16* a_w    = (__bf16*)(w + 42467328);      // 4,718,592
  __bf16* padb   = (__bf16*)(w + 47185920);      // 19,668,992
  __bf16* wrot   = (__bf16*)(w + 66854912);      // 4,718,592
  __bf16* ya     = (__bf16*)(w + 75497472);      // 18,874,368
  __bf16* yb     = (__bf16*)(w + 94371840);      // 18,874,368
  __bf16* tmp1   = (__bf16*)(w + 113246208);     // 18,874,368
  __bf16* zb     = (__bf16*)(w);                 // 18,874,368 (after attention)
  __bf16* c1wb   = (__bf16*)(w + 132120576);     // 2,097,152
  __bf16* wqkvb  = (__bf16*)(w + 134217728);     // 655,360
  float* qkvbias = (float*)(w + 134873088);      // 2,560
  float* stats   = (float*)(w + 134875648);      // 512

  cast_rot_k<<<512, 256, 0, stream>>>(conv1w, c1wb, 256, 131072);
  wqkv_rot_k<<<160, 256, 0, stream>>>(qw, kw, vw, wqkvb);
  fuse_bias_k<<<3, 256, 0, stream>>>(qbias, kbias, vbias, qkvbias, stats);
  transpose_x_k<<<dim3(32, 144, 2), 256, 0, stream>>>(x, xt);

  {  // conv1: ya = xt @ c1wb^T + b (rotated out). 144 m-tiles x 8 n-tiles.
    GemmAP p{};
    p.A = xt; p.B = c1wb; p.C = ya; p.bias = conv1b;
    p.sAr = 2048; p.sBr = 2048; p.sCr = 512;
    p.K = 2048; p.ntn = 8;
    gemm_async_k<1><<<1152, 256, 0, stream>>>(p);
  }

  for (int it = 0; it < 2; it++) {
    __bf16* tin = it ? yb : ya;
    {  // fused qkv projection. 144 m-tiles x 10 n-tiles.
      GemmAP p{};
      p.A = tin; p.B = wqkvb; p.C = qkv; p.bias = qkvbias;
      p.sAr = 512; p.sBr = 512; p.sCr = 640;
      p.K = 512; p.ntn = 10;
      gemm_async_k<0><<<1440, 256, 0, stream>>>(p);
    }
    cc_scores_k<<<dim3(192, 2), 384, 0, stream>>>(qkv, attnfH, attnfW);
    cc_softmax_k<<<4608, 256, 0, stream>>>(attnfH, attnfW, a_h, a_w);
    {  // agg1: per (b,w): tmp1[b][h][w][c] = sum_i a_h[h,i] * v[b,i,w,c]
      AggP p{};
      p.A = a_h; p.B = qkv + 128; p.C = tmp1;
      p.bB1 = (long long)9216 * 640; p.bB2 = 640; p.sBr = (long long)96 * 640;
      p.cB1 = (long long)9216 * 512; p.cB2 = 512; p.sCr = (long long)96 * 512;
      agg_k<0><<<dim3(4, 1, 192), 256, 0, stream>>>(p);
    }
    {  // agg2 + epilogue: per (b,h)
      AggP p{};
      p.A = a_w; p.B = qkv + 128;
      p.bB1 = (long long)9216 * 640; p.bB2 = (long long)96 * 640; p.sBr = 640;
      p.cB1 = (long long)9216 * 512; p.cB2 = (long long)96 * 512; p.sCr = 512;
      p.tmp = tmp1; p.res = tin; p.gma = gma;
      if (it == 0) {
        p.C = yb;
        agg_k<1><<<dim3(4, 1, 192), 256, 0, stream>>>(p);
      } else {
        p.C = padb;
        agg_k<2><<<dim3(4, 1, 192), 256, 0, stream>>>(p);
      }
    }
  }

  reorder_w_k<<<512, 256, 0, stream>>>(cow, wrot);
  border0_k<<<194, 256, 0, stream>>>(padb);
  conv3_gemm_k<<<576, 256, 0, stream>>>(padb, wrot, zb);
  gn_stats_k<<<256, 256, 0, stream>>>(zb, stats);
  gn_write_k<<<dim3(8, 96, 2), 256, 0, stream>>>(zb, stats, gng, gnb, out);
}

// Round 6
// 650.386 us; speedup vs baseline: 1.0659x; 1.0659x over previous
//
#include <hip/hip_runtime.h>
#include <hip/hip_bf16.h>

// CCAttention pipeline on MI355X. fp32 in/out, bf16 MFMA internal, NHWC.
// B=2, CIN=2048, CINT=512, CQK=64, H=W=96, S=9216, NG=32.
// R6: 128x64 tiles for conv1/qkv gemm_async (grid 1152/1440). KEPT.
// R7: gn_stats 256-block linear+atomic. KEPT.
// R9 (agg staging remap) REVERTED; R10 (explicit dbuf+counted vmcnt) REVERTED:
// conv3 105.7->173us -- 64KB LDS halved occupancy, VALU doubled, FETCH +50%.
// Confirms guide m99/m100/m132: 2-barrier stall is structural; wave-level
// overlap across co-resident blocks is the only lever at HIP source.
// R11: conv3 tiles 64(M)x128(N), grid 1152 (288 m x 4 n) = 4.5 blocks/CU
// (was 2.25, grid-limited). M-split (not N-split, the R1 failure): extra
// logical reads land on L2-resident wrot (4.6MB), A-panel (padb, HBM) reuse
// unchanged. LDS 24KB, MFMA:load 16:3 per thread (was 32:8).

typedef __bf16 bf8_t __attribute__((ext_vector_type(8)));
typedef float f32x4 __attribute__((ext_vector_type(4)));

union I4B8 { int4 i; bf8_t b; };

typedef const __attribute__((address_space(1))) void as1_cvoid;
typedef __attribute__((address_space(3))) void as3_void;
__device__ __forceinline__ void gload16(const void* g, void* l) {
  __builtin_amdgcn_global_load_lds((as1_cvoid*)g, (as3_void*)l, 16, 0, 0);
}
__device__ __forceinline__ int rot8(int c, int key) { return (c + key) & 7; }

// ---------------------------------------------------------------- weight prep
__global__ __launch_bounds__(256) void cast_rot_k(const float* s, __bf16* d, int K8, int total8) {
  int idx = blockIdx.x * 256 + threadIdx.x;
  if (idx >= total8) return;
  int c8 = idx % K8, n = idx / K8;
  int pos = rot8(c8 & 7, n & 7);
  const float* sp = s + ((long long)n * K8 + c8) * 8;
  float4 a = *(const float4*)sp, b = *(const float4*)(sp + 4);
  I4B8 u;
  u.b[0] = (__bf16)a.x; u.b[1] = (__bf16)a.y; u.b[2] = (__bf16)a.z; u.b[3] = (__bf16)a.w;
  u.b[4] = (__bf16)b.x; u.b[5] = (__bf16)b.y; u.b[6] = (__bf16)b.z; u.b[7] = (__bf16)b.w;
  *(int4*)(d + ((long long)n * K8 + (c8 & ~7) + pos) * 8) = u.i;
}

__global__ __launch_bounds__(256) void wqkv_rot_k(const float* qw, const float* kw, const float* vw, __bf16* d) {
  int idx = blockIdx.x * 256 + threadIdx.x;  // 640*64
  if (idx >= 640 * 64) return;
  int c8 = idx & 63, n = idx >> 6;
  const float* src = (n < 64) ? qw + (long long)n * 512
                   : (n < 128) ? kw + (long long)(n - 64) * 512
                               : vw + (long long)(n - 128) * 512;
  int pos = rot8(c8 & 7, n & 7);
  const float* sp = src + c8 * 8;
  float4 a = *(const float4*)sp, b = *(const float4*)(sp + 4);
  I4B8 u;
  u.b[0] = (__bf16)a.x; u.b[1] = (__bf16)a.y; u.b[2] = (__bf16)a.z; u.b[3] = (__bf16)a.w;
  u.b[4] = (__bf16)b.x; u.b[5] = (__bf16)b.y; u.b[6] = (__bf16)b.z; u.b[7] = (__bf16)b.w;
  *(int4*)(d + ((long long)n * 64 + (c8 & ~7) + pos) * 8) = u.i;
}

// also zeroes the 128-float stats accumulator (consumed much later by gn)
__global__ __launch_bounds__(256) void fuse_bias_k(const float* qb, const float* kb, const float* vb,
                                                   float* d, float* stats) {
  int i = blockIdx.x * 256 + threadIdx.x;
  if (i < 128) stats[i] = 0.f;
  if (i >= 640) return;
  d[i] = (i < 64) ? qb[i] : (i < 128) ? kb[i - 64] : vb[i - 128];
}

// conv3 weights -> wr[o][dydx*512+c] rotated by o&7; coalesced via LDS.
__global__ __launch_bounds__(256) void reorder_w_k(const float* w, __bf16* wr) {
  __shared__ float ls[4608];
  int o = blockIdx.x;
  int t = threadIdx.x;
  const float* base = w + (long long)o * 4608;
#pragma unroll
  for (int i = 0; i < 18; i++) ls[t + i * 256] = base[t + i * 256];
  __syncthreads();
#pragma unroll
  for (int i = 0; i < 3; i++) {
    int q = t + i * 256;
    if (q >= 576) break;
    int k0 = q * 8;
    int dydx = k0 / 512, c0 = k0 & 511;
    I4B8 u;
#pragma unroll
    for (int j = 0; j < 8; j++) u.b[j] = (__bf16)ls[(c0 + j) * 9 + dydx];
    int pos = rot8((k0 >> 3) & 7, o & 7);
    *(int4*)(wr + (long long)o * 4608 + (k0 & ~63) + pos * 8) = u.i;
  }
}

// x f32 NCHW -> xt bf16 NHWC, rotated by pixel&7.
__global__ __launch_bounds__(256) void transpose_x_k(const float* x, __bf16* xt) {
  __shared__ __bf16 l[64 * 66];
  int c0 = blockIdx.x * 64, s0 = blockIdx.y * 64, b = blockIdx.z;
  int t = threadIdx.x;
#pragma unroll
  for (int i = 0; i < 2; i++) {
    int slot = t + i * 256;
    int cl = slot >> 3, sch = slot & 7;
    const float* src = x + ((long long)(b * 2048 + c0 + cl)) * 9216 + s0 + sch * 8;
    float4 a = *(const float4*)src, bb = *(const float4*)(src + 4);
    __bf16* dst = &l[cl * 66 + sch * 8];
    dst[0] = (__bf16)a.x; dst[1] = (__bf16)a.y; dst[2] = (__bf16)a.z; dst[3] = (__bf16)a.w;
    dst[4] = (__bf16)bb.x; dst[5] = (__bf16)bb.y; dst[6] = (__bf16)bb.z; dst[7] = (__bf16)bb.w;
  }
  __syncthreads();
#pragma unroll
  for (int i = 0; i < 2; i++) {
    int slot = t + i * 256;
    int sl = slot >> 3, cch = slot & 7;
    I4B8 u;
#pragma unroll
    for (int j = 0; j < 8; j++) u.b[j] = l[(cch * 8 + j) * 66 + sl];
    *(int4*)(xt + ((long long)(b * 9216 + s0 + sl)) * 2048 + c0 + rot8(cch, sl & 7) * 8) = u.i;
  }
}

// zero the padb border pixels (interior is written by agg2 it=1)
__global__ __launch_bounds__(256) void border0_k(__bf16* padb) {
  int idx = blockIdx.x * 256 + threadIdx.x;  // 776 border pixels * 64 int4
  if (idx >= 776 * 64) return;
  int ch = idx & 63, bi = idx >> 6;
  int b = bi / 388, r = bi % 388;
  int hh, ww;
  if (r < 98) { hh = 0; ww = r; }
  else if (r < 196) { hh = 97; ww = r - 98; }
  else if (r < 292) { hh = r - 196 + 1; ww = 0; }
  else { hh = r - 292 + 1; ww = 97; }
  *(int4*)(padb + ((long long)(b * 9604 + hh * 98 + ww)) * 512 + ch * 8) = make_int4(0, 0, 0, 0);
}

// ---------------------------------------------------------------- async GEMM
// 128(M)x64(N) tiles, 4 waves in 2x2, wave tile 64x32, acc[4][2]. [R2 form]
struct GemmAP {
  const __bf16 *A, *B;
  __bf16* C;
  const float* bias;
  long long sAr, sBr, sCr;
  int K, ntn;
};

template <int CROT>
__global__ __launch_bounds__(256) void gemm_async_k(GemmAP p) {
  __shared__ __attribute__((aligned(16))) __bf16 lA[128 * 64];
  __shared__ __attribute__((aligned(16))) __bf16 lB[64 * 64];
  const int t = threadIdx.x;
  const int id = blockIdx.x;
  const int per8 = gridDim.x >> 3;
  const int lin = (id & 7) * per8 + (id >> 3);
  const int m0 = (lin / p.ntn) * 128, n0 = (lin % p.ntn) * 64;
  const int lane = t & 63, wave = t >> 6;
  const int wm = (wave >> 1) * 64, wn = (wave & 1) * 32;
  const int l15 = lane & 15, l4 = lane >> 4;
  const int srow = (lane >> 3), schunk = (lane & 7) * 8;
  f32x4 acc[4][2];
#pragma unroll
  for (int i = 0; i < 4; i++)
#pragma unroll
    for (int j = 0; j < 2; j++) acc[i][j] = f32x4{0.f, 0.f, 0.f, 0.f};

  for (int kb = 0; kb < p.K; kb += 64) {
    const int rbA = wave * 32, rbB = wave * 16;
#pragma unroll
    for (int i = 0; i < 4; i++) {
      int row = rbA + i * 8;
      gload16(p.A + (long long)(m0 + row + srow) * p.sAr + kb + schunk, &lA[row * 64]);
    }
#pragma unroll
    for (int i = 0; i < 2; i++) {
      int row = rbB + i * 8;
      gload16(p.B + (long long)(n0 + row + srow) * p.sBr + kb + schunk, &lB[row * 64]);
    }
    __syncthreads();
#pragma unroll
    for (int kk = 0; kk < 2; kk++) {
      bf8_t af[4], bfr[2];
      int cch = kk * 4 + l4;
#pragma unroll
      for (int mt = 0; mt < 4; mt++) {
        int r = wm + mt * 16 + l15;
        af[mt] = *(bf8_t*)&lA[r * 64 + (rot8(cch, r & 7) << 3)];
      }
#pragma unroll
      for (int nt = 0; nt < 2; nt++) {
        int r = wn + nt * 16 + l15;
        bfr[nt] = *(bf8_t*)&lB[r * 64 + (rot8(cch, r & 7) << 3)];
      }
#pragma unroll
      for (int mt = 0; mt < 4; mt++)
#pragma unroll
        for (int nt = 0; nt < 2; nt++)
          acc[mt][nt] = __builtin_amdgcn_mfma_f32_16x16x32_bf16(af[mt], bfr[nt], acc[mt][nt], 0, 0, 0);
    }
    __syncthreads();
  }
#pragma unroll
  for (int nt = 0; nt < 2; nt++) {
    int col = n0 + wn + nt * 16 + l15;
    float bv = p.bias[col];
#pragma unroll
    for (int mt = 0; mt < 4; mt++) {
      int row0 = m0 + wm + mt * 16 + (l4 << 2);
#pragma unroll
      for (int r = 0; r < 4; r++) {
        int row = row0 + r;
        int pc = CROT ? (col & ~63) + (rot8((col >> 3) & 7, row & 7) << 3) + (col & 7) : col;
        p.C[(long long)row * p.sCr + pc] = (__bf16)(acc[mt][nt][r] + bv);
      }
    }
  }
}

// ---------------------------------------------------------------- agg GEMM
// Batched 96(M)x512(N)x128(Kpad) GEMM. A (a_h/a_w): rows pre-rotated (key
// row&7), padded K=128, batch stride 96*128 -> async staging. B: V section
// of qkv, transposed-in-LDS (k rows, guard k<96 -> zeros).  [R2 staging]
// MODE 0: C=acc (tmp1). MODE 1: C[rot]=g*(tmp+acc)+res. MODE 2: same but
// store into padb at (h+1,w+1) with key (w+1)&7.
struct AggP {
  const __bf16 *A, *B;  // B = qkv + 128 (V columns)
  __bf16* C;
  const __bf16 *tmp, *res;
  const float* gma;
  long long bB1, bB2, sBr;
  long long cB1, cB2, sCr;
};

template <int MODE>
__global__ __launch_bounds__(256) void agg_k(AggP p) {
  __shared__ __attribute__((aligned(16))) __bf16 lA[128 * 64];
  __shared__ __attribute__((aligned(16))) __bf16 lB[128 * 64];
  const int t = threadIdx.x;
  const int z = blockIdx.z;
  const int z1 = z / 96, z2 = z % 96;
  const __bf16* A = p.A + (long long)z * (96 * 128);
  const __bf16* B = p.B + (long long)z1 * p.bB1 + (long long)z2 * p.bB2;
  const int n0 = blockIdx.x * 128;
  const int lane = t & 63, wave = t >> 6;
  const int wm = (wave >> 1) * 64, wn = (wave & 1) * 64;
  const int l15 = lane & 15, l4 = lane >> 4;
  const int srow = lane >> 3, schunk = (lane & 7) * 8;
  f32x4 acc[4][4];
#pragma unroll
  for (int i = 0; i < 4; i++)
#pragma unroll
    for (int j = 0; j < 4; j++) acc[i][j] = f32x4{0.f, 0.f, 0.f, 0.f};

#pragma unroll
  for (int kb = 0; kb < 128; kb += 64) {
    const int rb = wave * 32;
#pragma unroll
    for (int i = 0; i < 4; i++) {
      int row = rb + i * 8;
      gload16(A + (long long)(row + srow) * 128 + kb + schunk, &lA[row * 64]);
    }
#pragma unroll
    for (int i = 0; i < 4; i++) {
      int slot = t + i * 256;
      int kl = slot & 63, cch = slot >> 6;
      int gk = kb + kl;
      I4B8 u;
      u.i = make_int4(0, 0, 0, 0);
      if (gk < 96) u.i = *(const int4*)(B + (long long)gk * p.sBr + n0 + cch * 8);
#pragma unroll
      for (int j = 0; j < 8; j++) {
        int n = cch * 8 + j;
        lB[n * 64 + (rot8(kl >> 3, n & 7) << 3) + (kl & 7)] = u.b[j];
      }
    }
    __syncthreads();
#pragma unroll
    for (int kk = 0; kk < 2; kk++) {
      bf8_t af[4], bfr[4];
      int cch = kk * 4 + l4;
#pragma unroll
      for (int mt = 0; mt < 4; mt++) {
        int r = wm + mt * 16 + l15;
        af[mt] = *(bf8_t*)&lA[r * 64 + (rot8(cch, r & 7) << 3)];
      }
#pragma unroll
      for (int nt = 0; nt < 4; nt++) {
        int r = wn + nt * 16 + l15;
        bfr[nt] = *(bf8_t*)&lB[r * 64 + (rot8(cch, r & 7) << 3)];
      }
#pragma unroll
      for (int mt = 0; mt < 4; mt++)
#pragma unroll
        for (int nt = 0; nt < 4; nt++)
          acc[mt][nt] = __builtin_amdgcn_mfma_f32_16x16x32_bf16(af[mt], bfr[nt], acc[mt][nt], 0, 0, 0);
    }
    __syncthreads();
  }
  long long cbase = (long long)z1 * p.cB1 + (long long)z2 * p.cB2;
  float g = MODE ? *p.gma : 0.f;
#pragma unroll
  for (int nt = 0; nt < 4; nt++) {
    int col = n0 + wn + nt * 16 + l15;
#pragma unroll
    for (int mt = 0; mt < 4; mt++) {
      int row0 = wm + mt * 16 + (l4 << 2);
#pragma unroll
      for (int r = 0; r < 4; r++) {
        int row = row0 + r;
        if (row >= 96) continue;
        long long offL = cbase + (long long)row * p.sCr + col;
        float v = acc[mt][nt][r];
        if (MODE == 0) {
          p.C[offL] = (__bf16)v;
        } else {
          int rc = (col & ~63) + (rot8((col >> 3) & 7, row & 7) << 3) + (col & 7);
          long long offP = cbase + (long long)row * p.sCr + rc;
          v = g * ((float)p.tmp[offL] + v) + (float)p.res[offP];
          if (MODE == 1) {
            p.C[offP] = (__bf16)v;
          } else {
            int pc = (col & ~63) + (rot8((col >> 3) & 7, (row + 1) & 7) << 3) + (col & 7);
            long long pidx = (long long)z1 * 9604 + (long long)(z2 + 1) * 98 + (row + 1);
            p.C[pidx * 512 + pc] = (__bf16)v;
          }
        }
      }
    }
  }
}

// ---------------------------------------------------------------- scores
// mode 0 (b,w): E[h][i] (diag -inf) -> attnfH[b*96+w][h*96+i]
// mode 1 (b,h): E[w][j]             -> attnfW[b*96+h][w*96+j]
__global__ __launch_bounds__(384) void cc_scores_k(const __bf16* qkv, float* attnfH, float* attnfW) {
  __shared__ __attribute__((aligned(16))) __bf16 Qs[96 * 64];
  __shared__ __attribute__((aligned(16))) __bf16 Ks[96 * 64];
  int bfi = blockIdx.x;
  int b = bfi / 96, f = bfi % 96;
  int mode = blockIdx.y;
  long long base = (mode == 0) ? ((long long)(b * 9216 + f)) * 640 : ((long long)(b * 9216 + f * 96)) * 640;
  long long rstr = (mode == 0) ? 96 * 640 : 640;
  int t = threadIdx.x;
#pragma unroll
  for (int i = 0; i < 2; i++) {
    int slot = t + i * 384;
    int r = slot >> 3, c = slot & 7;
    int sw = rot8(c, r & 7) << 3;
    *(int4*)&Qs[r * 64 + sw] = *(const int4*)(qkv + base + (long long)r * rstr + c * 8);
    *(int4*)&Ks[r * 64 + sw] = *(const int4*)(qkv + base + (long long)r * rstr + 64 + c * 8);
  }
  __syncthreads();
  int lane = t & 63, wave = t >> 6;
  int l15 = lane & 15, l4 = lane >> 4;
  f32x4 acc[6];
#pragma unroll
  for (int i = 0; i < 6; i++) acc[i] = f32x4{0.f, 0.f, 0.f, 0.f};
#pragma unroll
  for (int kk = 0; kk < 2; kk++) {
    int ar = wave * 16 + l15;
    int cch = kk * 4 + l4;
    bf8_t af = *(bf8_t*)&Qs[ar * 64 + (rot8(cch, ar & 7) << 3)];
#pragma unroll
    for (int nt = 0; nt < 6; nt++) {
      int br = nt * 16 + l15;
      bf8_t bfr = *(bf8_t*)&Ks[br * 64 + (rot8(cch, br & 7) << 3)];
      acc[nt] = __builtin_amdgcn_mfma_f32_16x16x32_bf16(af, bfr, acc[nt], 0, 0, 0);
    }
  }
  float* dst = (mode == 0 ? attnfH : attnfW) + (long long)bfi * 9216;
#pragma unroll
  for (int nt = 0; nt < 6; nt++) {
#pragma unroll
    for (int r = 0; r < 4; r++) {
      int m = wave * 16 + (l4 << 2) + r;
      int n = nt * 16 + l15;
      float v = acc[nt][r];
      if (mode == 0 && n == m) v = -__builtin_inff();
      dst[m * 96 + n] = v;
    }
  }
}

// softmax over concat[e_h, e_w] (192), writes padded+rotated a_h/a_w rows.
__global__ __launch_bounds__(256) void cc_softmax_k(const float* attnfH, const float* attnfW,
                                                    __bf16* a_h, __bf16* a_w) {
  int wave = threadIdx.x >> 6, lane = threadIdx.x & 63;
  int pix = blockIdx.x * 4 + wave;
  int b = pix / 9216, hw = pix % 9216;
  int h = hw / 96, w2 = hw % 96;
  const float* ehb = attnfH + ((long long)(b * 96 + w2)) * 9216 + h * 96;
  const float* ewb = attnfW + ((long long)(b * 96 + h)) * 9216 + w2 * 96;
  float x0 = ehb[lane];
  float x1 = lane < 32 ? ehb[64 + lane] : -__builtin_inff();
  float x2 = ewb[lane];
  float x3 = lane < 32 ? ewb[64 + lane] : -__builtin_inff();
  float m = fmaxf(fmaxf(x0, x1), fmaxf(x2, x3));
#pragma unroll
  for (int o = 32; o; o >>= 1) m = fmaxf(m, __shfl_xor(m, o));
  float e0 = __expf(x0 - m), e1 = __expf(x1 - m), e2 = __expf(x2 - m), e3 = __expf(x3 - m);
  float s = e0 + e1 + e2 + e3;
#pragma unroll
  for (int o = 32; o; o >>= 1) s += __shfl_xor(s, o);
  float inv = 1.f / s;
  // a_h row (h), key h&7 ; a_w row (w2), key w2&7
  __bf16* dh = a_h + ((long long)((b * 96 + w2) * 96 + h)) * 128;
  __bf16* dw = a_w + ((long long)((b * 96 + h) * 96 + w2)) * 128;
  int kh = h & 7, kw2 = w2 & 7;
  int k1 = lane, k2 = 64 + lane;
  int p1h = (k1 & ~63) + (rot8((k1 >> 3) & 7, kh) << 3) + (k1 & 7);
  int p2h = (k2 & ~63) + (rot8((k2 >> 3) & 7, kh) << 3) + (k2 & 7);
  int p1w = (k1 & ~63) + (rot8((k1 >> 3) & 7, kw2) << 3) + (k1 & 7);
  int p2w = (k2 & ~63) + (rot8((k2 >> 3) & 7, kw2) << 3) + (k2 & 7);
  dh[p1h] = (__bf16)(e0 * inv);
  dh[p2h] = (__bf16)(lane < 32 ? e1 * inv : 0.f);
  dw[p1w] = (__bf16)(e2 * inv);
  dw[p2w] = (__bf16)(lane < 32 ? e3 * inv : 0.f);
}

// ---------------------------------------------------------------- conv3x3
// R11: 64(M)x128(N) tiles, grid 1152 (288 m x 4 n) = 4.5 blocks/CU.
// 4 waves in 2x2, wave tile 32x64, acc[2][4]. LDS 24KB. Single-buffered
// 2-barrier K-loop (the proven structure).
__global__ __launch_bounds__(256) void conv3_gemm_k(const __bf16* pin, const __bf16* wr, __bf16* C) {
  __shared__ __attribute__((aligned(16))) __bf16 lA[64 * 64];
  __shared__ __attribute__((aligned(16))) __bf16 lB[128 * 64];
  const int t = threadIdx.x;
  const int id = blockIdx.x;
  const int per8 = gridDim.x >> 3;                 // 144
  const int lin = (id & 7) * per8 + (id >> 3);
  const int m0 = (lin >> 2) * 64, n0 = (lin & 3) * 128;
  const int lane = t & 63, wave = t >> 6;
  const int wm = (wave >> 1) * 32, wn = (wave & 1) * 64;
  const int l15 = lane & 15, l4 = lane >> 4;
  const int srow = lane >> 3, schunk = (lane & 7) * 8;
  const int rbA = wave * 16, rbB = wave * 32;
  f32x4 acc[2][4];
#pragma unroll
  for (int i = 0; i < 2; i++)
#pragma unroll
    for (int j = 0; j < 4; j++) acc[i][j] = f32x4{0.f, 0.f, 0.f, 0.f};
  long long sbase[2], bbase[4];
#pragma unroll
  for (int i = 0; i < 2; i++) {
    int r = rbA + i * 8 + srow;
    int m = m0 + r;
    int b = m / 9216, hw = m % 9216;
    int h = hw / 96, w2 = hw % 96;
    sbase[i] = ((long long)b * 9604 + h * 98 + w2) * 512 + schunk;
  }
#pragma unroll
  for (int i = 0; i < 4; i++) {
    int r = rbB + i * 8 + srow;
    bbase[i] = (long long)(n0 + r) * 4608 + schunk;
  }
  int w2f[2];
#pragma unroll
  for (int mt = 0; mt < 2; mt++) w2f[mt] = (m0 + wm + mt * 16 + l15) % 96;

  int kt = 0;
  for (int tap = 0; tap < 9; tap++) {
    const int dy = tap / 3, dx = tap - dy * 3;
    const long long aoff = (long long)(dy * 98 + dx) * 512;
    int keyA[2];
#pragma unroll
    for (int mt = 0; mt < 2; mt++) keyA[mt] = (w2f[mt] + dx) & 7;
    for (int sl = 0; sl < 8; sl++, kt++) {
      const int c0k = sl * 64;
#pragma unroll
      for (int i = 0; i < 2; i++)
        gload16(pin + sbase[i] + aoff + c0k, &lA[(rbA + i * 8) * 64]);
#pragma unroll
      for (int i = 0; i < 4; i++)
        gload16(wr + bbase[i] + kt * 64, &lB[(rbB + i * 8) * 64]);
      __syncthreads();
#pragma unroll
      for (int kk = 0; kk < 2; kk++) {
        bf8_t af[2], bfr[4];
        int cch = kk * 4 + l4;
#pragma unroll
        for (int mt = 0; mt < 2; mt++) {
          int r = wm + mt * 16 + l15;
          af[mt] = *(bf8_t*)&lA[r * 64 + (rot8(cch, keyA[mt]) << 3)];
        }
#pragma unroll
        for (int nt = 0; nt < 4; nt++) {
          int r = wn + nt * 16 + l15;
          bfr[nt] = *(bf8_t*)&lB[r * 64 + (rot8(cch, r & 7) << 3)];
        }
#pragma unroll
        for (int mt = 0; mt < 2; mt++)
#pragma unroll
          for (int nt = 0; nt < 4; nt++)
            acc[mt][nt] = __builtin_amdgcn_mfma_f32_16x16x32_bf16(af[mt], bfr[nt], acc[mt][nt], 0, 0, 0);
      }
      __syncthreads();
    }
  }
#pragma unroll
  for (int nt = 0; nt < 4; nt++) {
    int col = n0 + wn + nt * 16 + l15;
#pragma unroll
    for (int mt = 0; mt < 2; mt++) {
      int row0 = m0 + wm + mt * 16 + (l4 << 2);
#pragma unroll
      for (int r = 0; r < 4; r++) {
        int row = row0 + r;
        C[(long long)row * 512 + col] = (__bf16)acc[mt][nt][r];
      }
    }
  }
}

// ---------------------------------------------------------------- GroupNorm
// 256 blocks (1/CU), fully linear coalesced int4 reads; atomicAdd partials.
__global__ __launch_bounds__(256) void gn_stats_k(const __bf16* z, float* stats) {
  int bi = blockIdx.x, t = threadIdx.x;
  const __bf16* base = z + (long long)bi * (72 * 512);
  int g = (t & 63) >> 1;  // channel octet (t&63)*8 -> group
  float s = 0.f, ss = 0.f;
#pragma unroll
  for (int i = 0; i < 18; i++) {
    I4B8 u;
    u.i = *(const int4*)(base + ((long long)(t + i * 256)) * 8);
#pragma unroll
    for (int j = 0; j < 8; j++) {
      float f = (float)u.b[j];
      s += f;
      ss += f * f;
    }
  }
  s += __shfl_xor(s, 1);
  ss += __shfl_xor(ss, 1);
  __shared__ float red[2][4][32];
  int wave = t >> 6, lane = t & 63;
  if (!(lane & 1)) {
    red[0][wave][g] = s;
    red[1][wave][g] = ss;
  }
  __syncthreads();
  if (t < 32) {
    float S = red[0][0][t] + red[0][1][t] + red[0][2][t] + red[0][3][t];
    float SS = red[1][0][t] + red[1][1][t] + red[1][2][t] + red[1][3][t];
    int b = bi >> 7;  // 128 blocks per batch (72*128 = 9216 px)
    atomicAdd(&stats[2 * (b * 32 + t)], S);
    atomicAdd(&stats[2 * (b * 32 + t) + 1], SS);
  }
}

__global__ __launch_bounds__(256) void gn_write_k(const __bf16* z, const float* stats,
                                                 const float* gng, const float* gnb, float* out) {
  __shared__ __bf16 l[64 * 98];
  int c0 = blockIdx.x * 64, h = blockIdx.y, b = blockIdx.z;
  int t = threadIdx.x;
#pragma unroll
  for (int i = 0; i < 3; i++) {
    int slot = t + i * 256;
    int wl = slot >> 3, cch = slot & 7;
    I4B8 u;
    u.i = *(const int4*)(z + ((long long)(b * 9216 + h * 96 + wl)) * 512 + c0 + cch * 8);
#pragma unroll
    for (int j = 0; j < 8; j++) l[(cch * 8 + j) * 98 + wl] = u.b[j];
  }
  __syncthreads();
  const float inv = 1.f / 147456.f;
#pragma unroll
  for (int i = 0; i < 3; i++) {
    int slot = t + i * 256;
    int wch = slot % 12, cl = slot / 12;
    int c = c0 + cl;
    int g = c >> 4;
    float S = stats[2 * (b * 32 + g)], SS = stats[2 * (b * 32 + g) + 1];
    float mean = S * inv;
    float rstd = rsqrtf(SS * inv - mean * mean + 1e-5f);
    float sc = rstd * gng[c];
    float sh = gnb[c] - mean * sc;
    float4 o0, o1;
    const __bf16* src = &l[cl * 98 + wch * 8];
    o0.x = (float)src[0] * sc + sh; o0.y = (float)src[1] * sc + sh;
    o0.z = (float)src[2] * sc + sh; o0.w = (float)src[3] * sc + sh;
    o1.x = (float)src[4] * sc + sh; o1.y = (float)src[5] * sc + sh;
    o1.z = (float)src[6] * sc + sh; o1.w = (float)src[7] * sc + sh;
    float* dst = out + ((long long)((b * 512 + c) * 96 + h)) * 96 + wch * 8;
    *(float4*)dst = o0;
    *(float4*)(dst + 4) = o1;
  }
}

// ---------------------------------------------------------------- launch
extern "C" void kernel_launch(void* const* d_in, const int* in_sizes, int n_in,
                              void* d_out, int out_size, void* d_ws, size_t ws_size,
                              hipStream_t stream) {
  (void)in_sizes; (void)n_in; (void)out_size;
  const float* x = (const float*)d_in[0];
  const float* conv1w = (const float*)d_in[1];
  const float* conv1b = (const float*)d_in[2];
  const float* qw = (const float*)d_in[3];
  const float* qbias = (const float*)d_in[4];
  const float* kw = (const float*)d_in[5];
  const float* kbias = (const float*)d_in[6];
  const float* vw = (const float*)d_in[7];
  const float* vbias = (const float*)d_in[8];
  const float* gma = (const float*)d_in[9];
  const float* cow = (const float*)d_in[10];
  const float* gng = (const float*)d_in[11];
  const float* gnb = (const float*)d_in[12];
  float* out = (float*)d_out;

  if (ws_size < 134876160ULL) return;

  char* w = (char*)d_ws;
  __bf16* xt     = (__bf16*)(w);                 // 75,497,472 (phase 1)
  __bf16* qkv    = (__bf16*)(w);                 // 23,592,960
  float* attnfH  = (float*)(w + 23592960);       // 7,077,888
  float* attnfW  = (float*)(w + 30670848);       // 7,077,888
  __bf16* a_h    = (__bf16*)(w + 37748736);      // 4,718,592
  __bf16* a_w    = (__bf16*)(w + 42467328);      // 4,718,592
  __bf16* padb   = (__bf16*)(w + 47185920);      // 19,668,992
  __bf16* wrot   = (__bf16*)(w + 66854912);      // 4,718,592
  __bf16* ya     = (__bf16*)(w + 75497472);      // 18,874,368
  __bf16* yb     = (__bf16*)(w + 94371840);      // 18,874,368
  __bf16* tmp1   = (__bf16*)(w + 113246208);     // 18,874,368
  __bf16* zb     = (__bf16*)(w);                 // 18,874,368 (after attention)
  __bf16* c1wb   = (__bf16*)(w + 132120576);     // 2,097,152
  __bf16* wqkvb  = (__bf16*)(w + 134217728);     // 655,360
  float* qkvbias = (float*)(w + 134873088);      // 2,560
  float* stats   = (float*)(w + 134875648);      // 512

  cast_rot_k<<<512, 256, 0, stream>>>(conv1w, c1wb, 256, 131072);
  wqkv_rot_k<<<160, 256, 0, stream>>>(qw, kw, vw, wqkvb);
  fuse_bias_k<<<3, 256, 0, stream>>>(qbias, kbias, vbias, qkvbias, stats);
  transpose_x_k<<<dim3(32, 144, 2), 256, 0, stream>>>(x, xt);

  {  // conv1: ya = xt @ c1wb^T + b (rotated out). 144 m-tiles x 8 n-tiles.
    GemmAP p{};
    p.A = xt; p.B = c1wb; p.C = ya; p.bias = conv1b;
    p.sAr = 2048; p.sBr = 2048; p.sCr = 512;
    p.K = 2048; p.ntn = 8;
    gemm_async_k<1><<<1152, 256, 0, stream>>>(p);
  }

  for (int it = 0; it < 2; it++) {
    __bf16* tin = it ? yb : ya;
    {  // fused qkv projection. 144 m-tiles x 10 n-tiles.
      GemmAP p{};
      p.A = tin; p.B = wqkvb; p.C = qkv; p.bias = qkvbias;
      p.sAr = 512; p.sBr = 512; p.sCr = 640;
      p.K = 512; p.ntn = 10;
      gemm_async_k<0><<<1440, 256, 0, stream>>>(p);
    }
    cc_scores_k<<<dim3(192, 2), 384, 0, stream>>>(qkv, attnfH, attnfW);
    cc_softmax_k<<<4608, 256, 0, stream>>>(attnfH, attnfW, a_h, a_w);
    {  // agg1: per (b,w): tmp1[b][h][w][c] = sum_i a_h[h,i] * v[b,i,w,c]
      AggP p{};
      p.A = a_h; p.B = qkv + 128; p.C = tmp1;
      p.bB1 = (long long)9216 * 640; p.bB2 = 640; p.sBr = (long long)96 * 640;
      p.cB1 = (long long)9216 * 512; p.cB2 = 512; p.sCr = (long long)96 * 512;
      agg_k<0><<<dim3(4, 1, 192), 256, 0, stream>>>(p);
    }
    {  // agg2 + epilogue: per (b,h)
      AggP p{};
      p.A = a_w; p.B = qkv + 128;
      p.bB1 = (long long)9216 * 640; p.bB2 = (long long)96 * 640; p.sBr = 640;
      p.cB1 = (long long)9216 * 512; p.cB2 = (long long)96 * 512; p.sCr = 512;
      p.tmp = tmp1; p.res = tin; p.gma = gma;
      if (it == 0) {
        p.C = yb;
        agg_k<1><<<dim3(4, 1, 192), 256, 0, stream>>>(p);
      } else {
        p.C = padb;
        agg_k<2><<<dim3(4, 1, 192), 256, 0, stream>>>(p);
      }
    }
  }

  reorder_w_k<<<512, 256, 0, stream>>>(cow, wrot);
  border0_k<<<194, 256, 0, stream>>>(padb);
  conv3_gemm_k<<<1152, 256, 0, stream>>>(padb, wrot, zb);
  gn_stats_k<<<256, 256, 0, stream>>>(zb, stats);
  gn_write_k<<<dim3(8, 96, 2), 256, 0, stream>>>(zb, stats, gng, gnb, out);
}

// Round 7
// 616.947 us; speedup vs baseline: 1.1236x; 1.0542x over previous
//
#include <hip/hip_runtime.h>
#include <hip/hip_bf16.h>

// CCAttention pipeline on MI355X. fp32 in/out, bf16 MFMA internal, NHWC.
// B=2, CIN=2048, CINT=512, CQK=64, H=W=96, S=9216, NG=32.
// R6: 128x64 tiles for conv1/qkv gemm_async (grid 1152/1440). KEPT.
// R7: gn_stats 256-block linear+atomic. KEPT.
// REVERTED experiments: R8 vtrans (+14us), R9 agg remap (+15us), R10 explicit
// dbuf (+73us: LDS halved occupancy), R11 conv3 64x128 (+16us: B-mult x2
// leaked past 4MB L2, intensity halved).
// R12: conv3 at 96x128 tiles -- grid 768 (192m x 4n) = EXACTLY 3.0 blocks/CU,
// zero scheduling tail (R2's 576 = 2.25/CU ran a 64-block round at 25% util).
// Area x0.75 (intensity 24MFMA:7loads, -14%), B-mult x1.33 (vs R6's fatal x2),
// A (padb, HBM) multiplicity unchanged at 4.

typedef __bf16 bf8_t __attribute__((ext_vector_type(8)));
typedef float f32x4 __attribute__((ext_vector_type(4)));

union I4B8 { int4 i; bf8_t b; };

typedef const __attribute__((address_space(1))) void as1_cvoid;
typedef __attribute__((address_space(3))) void as3_void;
__device__ __forceinline__ void gload16(const void* g, void* l) {
  __builtin_amdgcn_global_load_lds((as1_cvoid*)g, (as3_void*)l, 16, 0, 0);
}
__device__ __forceinline__ int rot8(int c, int key) { return (c + key) & 7; }

// ---------------------------------------------------------------- weight prep
__global__ __launch_bounds__(256) void cast_rot_k(const float* s, __bf16* d, int K8, int total8) {
  int idx = blockIdx.x * 256 + threadIdx.x;
  if (idx >= total8) return;
  int c8 = idx % K8, n = idx / K8;
  int pos = rot8(c8 & 7, n & 7);
  const float* sp = s + ((long long)n * K8 + c8) * 8;
  float4 a = *(const float4*)sp, b = *(const float4*)(sp + 4);
  I4B8 u;
  u.b[0] = (__bf16)a.x; u.b[1] = (__bf16)a.y; u.b[2] = (__bf16)a.z; u.b[3] = (__bf16)a.w;
  u.b[4] = (__bf16)b.x; u.b[5] = (__bf16)b.y; u.b[6] = (__bf16)b.z; u.b[7] = (__bf16)b.w;
  *(int4*)(d + ((long long)n * K8 + (c8 & ~7) + pos) * 8) = u.i;
}

__global__ __launch_bounds__(256) void wqkv_rot_k(const float* qw, const float* kw, const float* vw, __bf16* d) {
  int idx = blockIdx.x * 256 + threadIdx.x;  // 640*64
  if (idx >= 640 * 64) return;
  int c8 = idx & 63, n = idx >> 6;
  const float* src = (n < 64) ? qw + (long long)n * 512
                   : (n < 128) ? kw + (long long)(n - 64) * 512
                               : vw + (long long)(n - 128) * 512;
  int pos = rot8(c8 & 7, n & 7);
  const float* sp = src + c8 * 8;
  float4 a = *(const float4*)sp, b = *(const float4*)(sp + 4);
  I4B8 u;
  u.b[0] = (__bf16)a.x; u.b[1] = (__bf16)a.y; u.b[2] = (__bf16)a.z; u.b[3] = (__bf16)a.w;
  u.b[4] = (__bf16)b.x; u.b[5] = (__bf16)b.y; u.b[6] = (__bf16)b.z; u.b[7] = (__bf16)b.w;
  *(int4*)(d + ((long long)n * 64 + (c8 & ~7) + pos) * 8) = u.i;
}

// also zeroes the 128-float stats accumulator (consumed much later by gn)
__global__ __launch_bounds__(256) void fuse_bias_k(const float* qb, const float* kb, const float* vb,
                                                   float* d, float* stats) {
  int i = blockIdx.x * 256 + threadIdx.x;
  if (i < 128) stats[i] = 0.f;
  if (i >= 640) return;
  d[i] = (i < 64) ? qb[i] : (i < 128) ? kb[i - 64] : vb[i - 128];
}

// conv3 weights -> wr[o][dydx*512+c] rotated by o&7; coalesced via LDS.
__global__ __launch_bounds__(256) void reorder_w_k(const float* w, __bf16* wr) {
  __shared__ float ls[4608];
  int o = blockIdx.x;
  int t = threadIdx.x;
  const float* base = w + (long long)o * 4608;
#pragma unroll
  for (int i = 0; i < 18; i++) ls[t + i * 256] = base[t + i * 256];
  __syncthreads();
#pragma unroll
  for (int i = 0; i < 3; i++) {
    int q = t + i * 256;
    if (q >= 576) break;
    int k0 = q * 8;
    int dydx = k0 / 512, c0 = k0 & 511;
    I4B8 u;
#pragma unroll
    for (int j = 0; j < 8; j++) u.b[j] = (__bf16)ls[(c0 + j) * 9 + dydx];
    int pos = rot8((k0 >> 3) & 7, o & 7);
    *(int4*)(wr + (long long)o * 4608 + (k0 & ~63) + pos * 8) = u.i;
  }
}

// x f32 NCHW -> xt bf16 NHWC, rotated by pixel&7.
__global__ __launch_bounds__(256) void transpose_x_k(const float* x, __bf16* xt) {
  __shared__ __bf16 l[64 * 66];
  int c0 = blockIdx.x * 64, s0 = blockIdx.y * 64, b = blockIdx.z;
  int t = threadIdx.x;
#pragma unroll
  for (int i = 0; i < 2; i++) {
    int slot = t + i * 256;
    int cl = slot >> 3, sch = slot & 7;
    const float* src = x + ((long long)(b * 2048 + c0 + cl)) * 9216 + s0 + sch * 8;
    float4 a = *(const float4*)src, bb = *(const float4*)(src + 4);
    __bf16* dst = &l[cl * 66 + sch * 8];
    dst[0] = (__bf16)a.x; dst[1] = (__bf16)a.y; dst[2] = (__bf16)a.z; dst[3] = (__bf16)a.w;
    dst[4] = (__bf16)bb.x; dst[5] = (__bf16)bb.y; dst[6] = (__bf16)bb.z; dst[7] = (__bf16)bb.w;
  }
  __syncthreads();
#pragma unroll
  for (int i = 0; i < 2; i++) {
    int slot = t + i * 256;
    int sl = slot >> 3, cch = slot & 7;
    I4B8 u;
#pragma unroll
    for (int j = 0; j < 8; j++) u.b[j] = l[(cch * 8 + j) * 66 + sl];
    *(int4*)(xt + ((long long)(b * 9216 + s0 + sl)) * 2048 + c0 + rot8(cch, sl & 7) * 8) = u.i;
  }
}

// zero the padb border pixels (interior is written by agg2 it=1)
__global__ __launch_bounds__(256) void border0_k(__bf16* padb) {
  int idx = blockIdx.x * 256 + threadIdx.x;  // 776 border pixels * 64 int4
  if (idx >= 776 * 64) return;
  int ch = idx & 63, bi = idx >> 6;
  int b = bi / 388, r = bi % 388;
  int hh, ww;
  if (r < 98) { hh = 0; ww = r; }
  else if (r < 196) { hh = 97; ww = r - 98; }
  else if (r < 292) { hh = r - 196 + 1; ww = 0; }
  else { hh = r - 292 + 1; ww = 97; }
  *(int4*)(padb + ((long long)(b * 9604 + hh * 98 + ww)) * 512 + ch * 8) = make_int4(0, 0, 0, 0);
}

// ---------------------------------------------------------------- async GEMM
// 128(M)x64(N) tiles, 4 waves in 2x2, wave tile 64x32, acc[4][2]. [R2 form]
struct GemmAP {
  const __bf16 *A, *B;
  __bf16* C;
  const float* bias;
  long long sAr, sBr, sCr;
  int K, ntn;
};

template <int CROT>
__global__ __launch_bounds__(256) void gemm_async_k(GemmAP p) {
  __shared__ __attribute__((aligned(16))) __bf16 lA[128 * 64];
  __shared__ __attribute__((aligned(16))) __bf16 lB[64 * 64];
  const int t = threadIdx.x;
  const int id = blockIdx.x;
  const int per8 = gridDim.x >> 3;
  const int lin = (id & 7) * per8 + (id >> 3);
  const int m0 = (lin / p.ntn) * 128, n0 = (lin % p.ntn) * 64;
  const int lane = t & 63, wave = t >> 6;
  const int wm = (wave >> 1) * 64, wn = (wave & 1) * 32;
  const int l15 = lane & 15, l4 = lane >> 4;
  const int srow = (lane >> 3), schunk = (lane & 7) * 8;
  f32x4 acc[4][2];
#pragma unroll
  for (int i = 0; i < 4; i++)
#pragma unroll
    for (int j = 0; j < 2; j++) acc[i][j] = f32x4{0.f, 0.f, 0.f, 0.f};

  for (int kb = 0; kb < p.K; kb += 64) {
    const int rbA = wave * 32, rbB = wave * 16;
#pragma unroll
    for (int i = 0; i < 4; i++) {
      int row = rbA + i * 8;
      gload16(p.A + (long long)(m0 + row + srow) * p.sAr + kb + schunk, &lA[row * 64]);
    }
#pragma unroll
    for (int i = 0; i < 2; i++) {
      int row = rbB + i * 8;
      gload16(p.B + (long long)(n0 + row + srow) * p.sBr + kb + schunk, &lB[row * 64]);
    }
    __syncthreads();
#pragma unroll
    for (int kk = 0; kk < 2; kk++) {
      bf8_t af[4], bfr[2];
      int cch = kk * 4 + l4;
#pragma unroll
      for (int mt = 0; mt < 4; mt++) {
        int r = wm + mt * 16 + l15;
        af[mt] = *(bf8_t*)&lA[r * 64 + (rot8(cch, r & 7) << 3)];
      }
#pragma unroll
      for (int nt = 0; nt < 2; nt++) {
        int r = wn + nt * 16 + l15;
        bfr[nt] = *(bf8_t*)&lB[r * 64 + (rot8(cch, r & 7) << 3)];
      }
#pragma unroll
      for (int mt = 0; mt < 4; mt++)
#pragma unroll
        for (int nt = 0; nt < 2; nt++)
          acc[mt][nt] = __builtin_amdgcn_mfma_f32_16x16x32_bf16(af[mt], bfr[nt], acc[mt][nt], 0, 0, 0);
    }
    __syncthreads();
  }
#pragma unroll
  for (int nt = 0; nt < 2; nt++) {
    int col = n0 + wn + nt * 16 + l15;
    float bv = p.bias[col];
#pragma unroll
    for (int mt = 0; mt < 4; mt++) {
      int row0 = m0 + wm + mt * 16 + (l4 << 2);
#pragma unroll
      for (int r = 0; r < 4; r++) {
        int row = row0 + r;
        int pc = CROT ? (col & ~63) + (rot8((col >> 3) & 7, row & 7) << 3) + (col & 7) : col;
        p.C[(long long)row * p.sCr + pc] = (__bf16)(acc[mt][nt][r] + bv);
      }
    }
  }
}

// ---------------------------------------------------------------- agg GEMM
// Batched 96(M)x512(N)x128(Kpad) GEMM. A (a_h/a_w): rows pre-rotated (key
// row&7), padded K=128, batch stride 96*128 -> async staging. B: V section
// of qkv, transposed-in-LDS (k rows, guard k<96 -> zeros).  [R2 staging]
// MODE 0: C=acc (tmp1). MODE 1: C[rot]=g*(tmp+acc)+res. MODE 2: same but
// store into padb at (h+1,w+1) with key (w+1)&7.
struct AggP {
  const __bf16 *A, *B;  // B = qkv + 128 (V columns)
  __bf16* C;
  const __bf16 *tmp, *res;
  const float* gma;
  long long bB1, bB2, sBr;
  long long cB1, cB2, sCr;
};

template <int MODE>
__global__ __launch_bounds__(256) void agg_k(AggP p) {
  __shared__ __attribute__((aligned(16))) __bf16 lA[128 * 64];
  __shared__ __attribute__((aligned(16))) __bf16 lB[128 * 64];
  const int t = threadIdx.x;
  const int z = blockIdx.z;
  const int z1 = z / 96, z2 = z % 96;
  const __bf16* A = p.A + (long long)z * (96 * 128);
  const __bf16* B = p.B + (long long)z1 * p.bB1 + (long long)z2 * p.bB2;
  const int n0 = blockIdx.x * 128;
  const int lane = t & 63, wave = t >> 6;
  const int wm = (wave >> 1) * 64, wn = (wave & 1) * 64;
  const int l15 = lane & 15, l4 = lane >> 4;
  const int srow = lane >> 3, schunk = (lane & 7) * 8;
  f32x4 acc[4][4];
#pragma unroll
  for (int i = 0; i < 4; i++)
#pragma unroll
    for (int j = 0; j < 4; j++) acc[i][j] = f32x4{0.f, 0.f, 0.f, 0.f};

#pragma unroll
  for (int kb = 0; kb < 128; kb += 64) {
    const int rb = wave * 32;
#pragma unroll
    for (int i = 0; i < 4; i++) {
      int row = rb + i * 8;
      gload16(A + (long long)(row + srow) * 128 + kb + schunk, &lA[row * 64]);
    }
#pragma unroll
    for (int i = 0; i < 4; i++) {
      int slot = t + i * 256;
      int kl = slot & 63, cch = slot >> 6;
      int gk = kb + kl;
      I4B8 u;
      u.i = make_int4(0, 0, 0, 0);
      if (gk < 96) u.i = *(const int4*)(B + (long long)gk * p.sBr + n0 + cch * 8);
#pragma unroll
      for (int j = 0; j < 8; j++) {
        int n = cch * 8 + j;
        lB[n * 64 + (rot8(kl >> 3, n & 7) << 3) + (kl & 7)] = u.b[j];
      }
    }
    __syncthreads();
#pragma unroll
    for (int kk = 0; kk < 2; kk++) {
      bf8_t af[4], bfr[4];
      int cch = kk * 4 + l4;
#pragma unroll
      for (int mt = 0; mt < 4; mt++) {
        int r = wm + mt * 16 + l15;
        af[mt] = *(bf8_t*)&lA[r * 64 + (rot8(cch, r & 7) << 3)];
      }
#pragma unroll
      for (int nt = 0; nt < 4; nt++) {
        int r = wn + nt * 16 + l15;
        bfr[nt] = *(bf8_t*)&lB[r * 64 + (rot8(cch, r & 7) << 3)];
      }
#pragma unroll
      for (int mt = 0; mt < 4; mt++)
#pragma unroll
        for (int nt = 0; nt < 4; nt++)
          acc[mt][nt] = __builtin_amdgcn_mfma_f32_16x16x32_bf16(af[mt], bfr[nt], acc[mt][nt], 0, 0, 0);
    }
    __syncthreads();
  }
  long long cbase = (long long)z1 * p.cB1 + (long long)z2 * p.cB2;
  float g = MODE ? *p.gma : 0.f;
#pragma unroll
  for (int nt = 0; nt < 4; nt++) {
    int col = n0 + wn + nt * 16 + l15;
#pragma unroll
    for (int mt = 0; mt < 4; mt++) {
      int row0 = wm + mt * 16 + (l4 << 2);
#pragma unroll
      for (int r = 0; r < 4; r++) {
        int row = row0 + r;
        if (row >= 96) continue;
        long long offL = cbase + (long long)row * p.sCr + col;
        float v = acc[mt][nt][r];
        if (MODE == 0) {
          p.C[offL] = (__bf16)v;
        } else {
          int rc = (col & ~63) + (rot8((col >> 3) & 7, row & 7) << 3) + (col & 7);
          long long offP = cbase + (long long)row * p.sCr + rc;
          v = g * ((float)p.tmp[offL] + v) + (float)p.res[offP];
          if (MODE == 1) {
            p.C[offP] = (__bf16)v;
          } else {
            int pc = (col & ~63) + (rot8((col >> 3) & 7, (row + 1) & 7) << 3) + (col & 7);
            long long pidx = (long long)z1 * 9604 + (long long)(z2 + 1) * 98 + (row + 1);
            p.C[pidx * 512 + pc] = (__bf16)v;
          }
        }
      }
    }
  }
}

// ---------------------------------------------------------------- scores
// mode 0 (b,w): E[h][i] (diag -inf) -> attnfH[b*96+w][h*96+i]
// mode 1 (b,h): E[w][j]             -> attnfW[b*96+h][w*96+j]
__global__ __launch_bounds__(384) void cc_scores_k(const __bf16* qkv, float* attnfH, float* attnfW) {
  __shared__ __attribute__((aligned(16))) __bf16 Qs[96 * 64];
  __shared__ __attribute__((aligned(16))) __bf16 Ks[96 * 64];
  int bfi = blockIdx.x;
  int b = bfi / 96, f = bfi % 96;
  int mode = blockIdx.y;
  long long base = (mode == 0) ? ((long long)(b * 9216 + f)) * 640 : ((long long)(b * 9216 + f * 96)) * 640;
  long long rstr = (mode == 0) ? 96 * 640 : 640;
  int t = threadIdx.x;
#pragma unroll
  for (int i = 0; i < 2; i++) {
    int slot = t + i * 384;
    int r = slot >> 3, c = slot & 7;
    int sw = rot8(c, r & 7) << 3;
    *(int4*)&Qs[r * 64 + sw] = *(const int4*)(qkv + base + (long long)r * rstr + c * 8);
    *(int4*)&Ks[r * 64 + sw] = *(const int4*)(qkv + base + (long long)r * rstr + 64 + c * 8);
  }
  __syncthreads();
  int lane = t & 63, wave = t >> 6;
  int l15 = lane & 15, l4 = lane >> 4;
  f32x4 acc[6];
#pragma unroll
  for (int i = 0; i < 6; i++) acc[i] = f32x4{0.f, 0.f, 0.f, 0.f};
#pragma unroll
  for (int kk = 0; kk < 2; kk++) {
    int ar = wave * 16 + l15;
    int cch = kk * 4 + l4;
    bf8_t af = *(bf8_t*)&Qs[ar * 64 + (rot8(cch, ar & 7) << 3)];
#pragma unroll
    for (int nt = 0; nt < 6; nt++) {
      int br = nt * 16 + l15;
      bf8_t bfr = *(bf8_t*)&Ks[br * 64 + (rot8(cch, br & 7) << 3)];
      acc[nt] = __builtin_amdgcn_mfma_f32_16x16x32_bf16(af, bfr, acc[nt], 0, 0, 0);
    }
  }
  float* dst = (mode == 0 ? attnfH : attnfW) + (long long)bfi * 9216;
#pragma unroll
  for (int nt = 0; nt < 6; nt++) {
#pragma unroll
    for (int r = 0; r < 4; r++) {
      int m = wave * 16 + (l4 << 2) + r;
      int n = nt * 16 + l15;
      float v = acc[nt][r];
      if (mode == 0 && n == m) v = -__builtin_inff();
      dst[m * 96 + n] = v;
    }
  }
}

// softmax over concat[e_h, e_w] (192), writes padded+rotated a_h/a_w rows.
__global__ __launch_bounds__(256) void cc_softmax_k(const float* attnfH, const float* attnfW,
                                                    __bf16* a_h, __bf16* a_w) {
  int wave = threadIdx.x >> 6, lane = threadIdx.x & 63;
  int pix = blockIdx.x * 4 + wave;
  int b = pix / 9216, hw = pix % 9216;
  int h = hw / 96, w2 = hw % 96;
  const float* ehb = attnfH + ((long long)(b * 96 + w2)) * 9216 + h * 96;
  const float* ewb = attnfW + ((long long)(b * 96 + h)) * 9216 + w2 * 96;
  float x0 = ehb[lane];
  float x1 = lane < 32 ? ehb[64 + lane] : -__builtin_inff();
  float x2 = ewb[lane];
  float x3 = lane < 32 ? ewb[64 + lane] : -__builtin_inff();
  float m = fmaxf(fmaxf(x0, x1), fmaxf(x2, x3));
#pragma unroll
  for (int o = 32; o; o >>= 1) m = fmaxf(m, __shfl_xor(m, o));
  float e0 = __expf(x0 - m), e1 = __expf(x1 - m), e2 = __expf(x2 - m), e3 = __expf(x3 - m);
  float s = e0 + e1 + e2 + e3;
#pragma unroll
  for (int o = 32; o; o >>= 1) s += __shfl_xor(s, o);
  float inv = 1.f / s;
  // a_h row (h), key h&7 ; a_w row (w2), key w2&7
  __bf16* dh = a_h + ((long long)((b * 96 + w2) * 96 + h)) * 128;
  __bf16* dw = a_w + ((long long)((b * 96 + h) * 96 + w2)) * 128;
  int kh = h & 7, kw2 = w2 & 7;
  int k1 = lane, k2 = 64 + lane;
  int p1h = (k1 & ~63) + (rot8((k1 >> 3) & 7, kh) << 3) + (k1 & 7);
  int p2h = (k2 & ~63) + (rot8((k2 >> 3) & 7, kh) << 3) + (k2 & 7);
  int p1w = (k1 & ~63) + (rot8((k1 >> 3) & 7, kw2) << 3) + (k1 & 7);
  int p2w = (k2 & ~63) + (rot8((k2 >> 3) & 7, kw2) << 3) + (k2 & 7);
  dh[p1h] = (__bf16)(e0 * inv);
  dh[p2h] = (__bf16)(lane < 32 ? e1 * inv : 0.f);
  dw[p1w] = (__bf16)(e2 * inv);
  dw[p2w] = (__bf16)(lane < 32 ? e3 * inv : 0.f);
}

// ---------------------------------------------------------------- conv3x3
// R12: 96(M)x128(N) tiles, grid 768 (192m x 4n) = exactly 3 blocks/CU.
// 4 waves in 2x2, wave tile 48x64, acc[3][4]. LDS 28KB. Single-buffered
// 2-barrier K-loop (proven structure).
__global__ __launch_bounds__(256) void conv3_gemm_k(const __bf16* pin, const __bf16* wr, __bf16* C) {
  __shared__ __attribute__((aligned(16))) __bf16 lA[96 * 64];
  __shared__ __attribute__((aligned(16))) __bf16 lB[128 * 64];
  const int t = threadIdx.x;
  const int id = blockIdx.x;
  const int per8 = gridDim.x >> 3;                 // 96
  const int lin = (id & 7) * per8 + (id >> 3);
  const int m0 = (lin >> 2) * 96, n0 = (lin & 3) * 128;
  const int lane = t & 63, wave = t >> 6;
  const int wm = (wave >> 1) * 48, wn = (wave & 1) * 64;
  const int l15 = lane & 15, l4 = lane >> 4;
  const int srow = lane >> 3, schunk = (lane & 7) * 8;
  const int rbA = wave * 24, rbB = wave * 32;
  f32x4 acc[3][4];
#pragma unroll
  for (int i = 0; i < 3; i++)
#pragma unroll
    for (int j = 0; j < 4; j++) acc[i][j] = f32x4{0.f, 0.f, 0.f, 0.f};
  long long sbase[3], bbase[4];
#pragma unroll
  for (int i = 0; i < 3; i++) {
    int r = rbA + i * 8 + srow;
    int m = m0 + r;
    int b = m / 9216, hw = m % 9216;
    int h = hw / 96, w2 = hw % 96;
    sbase[i] = ((long long)b * 9604 + h * 98 + w2) * 512 + schunk;
  }
#pragma unroll
  for (int i = 0; i < 4; i++) {
    int r = rbB + i * 8 + srow;
    bbase[i] = (long long)(n0 + r) * 4608 + schunk;
  }
  int w2f[3];
#pragma unroll
  for (int mt = 0; mt < 3; mt++) w2f[mt] = (m0 + wm + mt * 16 + l15) % 96;

  int kt = 0;
  for (int tap = 0; tap < 9; tap++) {
    const int dy = tap / 3, dx = tap - dy * 3;
    const long long aoff = (long long)(dy * 98 + dx) * 512;
    int keyA[3];
#pragma unroll
    for (int mt = 0; mt < 3; mt++) keyA[mt] = (w2f[mt] + dx) & 7;
    for (int sl = 0; sl < 8; sl++, kt++) {
      const int c0k = sl * 64;
#pragma unroll
      for (int i = 0; i < 3; i++)
        gload16(pin + sbase[i] + aoff + c0k, &lA[(rbA + i * 8) * 64]);
#pragma unroll
      for (int i = 0; i < 4; i++)
        gload16(wr + bbase[i] + kt * 64, &lB[(rbB + i * 8) * 64]);
      __syncthreads();
#pragma unroll
      for (int kk = 0; kk < 2; kk++) {
        bf8_t af[3], bfr[4];
        int cch = kk * 4 + l4;
#pragma unroll
        for (int mt = 0; mt < 3; mt++) {
          int r = wm + mt * 16 + l15;
          af[mt] = *(bf8_t*)&lA[r * 64 + (rot8(cch, keyA[mt]) << 3)];
        }
#pragma unroll
        for (int nt = 0; nt < 4; nt++) {
          int r = wn + nt * 16 + l15;
          bfr[nt] = *(bf8_t*)&lB[r * 64 + (rot8(cch, r & 7) << 3)];
        }
#pragma unroll
        for (int mt = 0; mt < 3; mt++)
#pragma unroll
          for (int nt = 0; nt < 4; nt++)
            acc[mt][nt] = __builtin_amdgcn_mfma_f32_16x16x32_bf16(af[mt], bfr[nt], acc[mt][nt], 0, 0, 0);
      }
      __syncthreads();
    }
  }
#pragma unroll
  for (int nt = 0; nt < 4; nt++) {
    int col = n0 + wn + nt * 16 + l15;
#pragma unroll
    for (int mt = 0; mt < 3; mt++) {
      int row0 = m0 + wm + mt * 16 + (l4 << 2);
#pragma unroll
      for (int r = 0; r < 4; r++) {
        int row = row0 + r;
        C[(long long)row * 512 + col] = (__bf16)acc[mt][nt][r];
      }
    }
  }
}

// ---------------------------------------------------------------- GroupNorm
// 256 blocks (1/CU), fully linear coalesced int4 reads; atomicAdd partials.
__global__ __launch_bounds__(256) void gn_stats_k(const __bf16* z, float* stats) {
  int bi = blockIdx.x, t = threadIdx.x;
  const __bf16* base = z + (long long)bi * (72 * 512);
  int g = (t & 63) >> 1;  // channel octet (t&63)*8 -> group
  float s = 0.f, ss = 0.f;
#pragma unroll
  for (int i = 0; i < 18; i++) {
    I4B8 u;
    u.i = *(const int4*)(base + ((long long)(t + i * 256)) * 8);
#pragma unroll
    for (int j = 0; j < 8; j++) {
      float f = (float)u.b[j];
      s += f;
      ss += f * f;
    }
  }
  s += __shfl_xor(s, 1);
  ss += __shfl_xor(ss, 1);
  __shared__ float red[2][4][32];
  int wave = t >> 6, lane = t & 63;
  if (!(lane & 1)) {
    red[0][wave][g] = s;
    red[1][wave][g] = ss;
  }
  __syncthreads();
  if (t < 32) {
    float S = red[0][0][t] + red[0][1][t] + red[0][2][t] + red[0][3][t];
    float SS = red[1][0][t] + red[1][1][t] + red[1][2][t] + red[1][3][t];
    int b = bi >> 7;  // 128 blocks per batch (72*128 = 9216 px)
    atomicAdd(&stats[2 * (b * 32 + t)], S);
    atomicAdd(&stats[2 * (b * 32 + t) + 1], SS);
  }
}

__global__ __launch_bounds__(256) void gn_write_k(const __bf16* z, const float* stats,
                                                 const float* gng, const float* gnb, float* out) {
  __shared__ __bf16 l[64 * 98];
  int c0 = blockIdx.x * 64, h = blockIdx.y, b = blockIdx.z;
  int t = threadIdx.x;
#pragma unroll
  for (int i = 0; i < 3; i++) {
    int slot = t + i * 256;
    int wl = slot >> 3, cch = slot & 7;
    I4B8 u;
    u.i = *(const int4*)(z + ((long long)(b * 9216 + h * 96 + wl)) * 512 + c0 + cch * 8);
#pragma unroll
    for (int j = 0; j < 8; j++) l[(cch * 8 + j) * 98 + wl] = u.b[j];
  }
  __syncthreads();
  const float inv = 1.f / 147456.f;
#pragma unroll
  for (int i = 0; i < 3; i++) {
    int slot = t + i * 256;
    int wch = slot % 12, cl = slot / 12;
    int c = c0 + cl;
    int g = c >> 4;
    float S = stats[2 * (b * 32 + g)], SS = stats[2 * (b * 32 + g) + 1];
    float mean = S * inv;
    float rstd = rsqrtf(SS * inv - mean * mean + 1e-5f);
    float sc = rstd * gng[c];
    float sh = gnb[c] - mean * sc;
    float4 o0, o1;
    const __bf16* src = &l[cl * 98 + wch * 8];
    o0.x = (float)src[0] * sc + sh; o0.y = (float)src[1] * sc + sh;
    o0.z = (float)src[2] * sc + sh; o0.w = (float)src[3] * sc + sh;
    o1.x = (float)src[4] * sc + sh; o1.y = (float)src[5] * sc + sh;
    o1.z = (float)src[6] * sc + sh; o1.w = (float)src[7] * sc + sh;
    float* dst = out + ((long long)((b * 512 + c) * 96 + h)) * 96 + wch * 8;
    *(float4*)dst = o0;
    *(float4*)(dst + 4) = o1;
  }
}

// ---------------------------------------------------------------- launch
extern "C" void kernel_launch(void* const* d_in, const int* in_sizes, int n_in,
                              void* d_out, int out_size, void* d_ws, size_t ws_size,
                              hipStream_t stream) {
  (void)in_sizes; (void)n_in; (void)out_size;
  const float* x = (const float*)d_in[0];
  const float* conv1w = (const float*)d_in[1];
  const float* conv1b = (const float*)d_in[2];
  const float* qw = (const float*)d_in[3];
  const float* qbias = (const float*)d_in[4];
  const float* kw = (const float*)d_in[5];
  const float* kbias = (const float*)d_in[6];
  const float* vw = (const float*)d_in[7];
  const float* vbias = (const float*)d_in[8];
  const float* gma = (const float*)d_in[9];
  const float* cow = (const float*)d_in[10];
  const float* gng = (const float*)d_in[11];
  const float* gnb = (const float*)d_in[12];
  float* out = (float*)d_out;

  if (ws_size < 134876160ULL) return;

  char* w = (char*)d_ws;
  __bf16* xt     = (__bf16*)(w);                 // 75,497,472 (phase 1)
  __bf16* qkv    = (__bf16*)(w);                 // 23,592,960
  float* attnfH  = (float*)(w + 23592960);       // 7,077,888
  float* attnfW  = (float*)(w + 30670848);       // 7,077,888
  __bf16* a_h    = (__bf16*)(w + 37748736);      // 4,718,592
  __bf16* a_w    = (__bf16*)(w + 42467328);      // 4,718,592
  __bf16* padb   = (__bf16*)(w + 47185920);      // 19,668,992
  __bf16* wrot   = (__bf16*)(w + 66854912);      // 4,718,592
  __bf16* ya     = (__bf16*)(w + 75497472);      // 18,874,368
  __bf16* yb     = (__bf16*)(w + 94371840);      // 18,874,368
  __bf16* tmp1   = (__bf16*)(w + 113246208);     // 18,874,368
  __bf16* zb     = (__bf16*)(w);                 // 18,874,368 (after attention)
  __bf16* c1wb   = (__bf16*)(w + 132120576);     // 2,097,152
  __bf16* wqkvb  = (__bf16*)(w + 134217728);     // 655,360
  float* qkvbias = (float*)(w + 134873088);      // 2,560
  float* stats   = (float*)(w + 134875648);      // 512

  cast_rot_k<<<512, 256, 0, stream>>>(conv1w, c1wb, 256, 131072);
  wqkv_rot_k<<<160, 256, 0, stream>>>(qw, kw, vw, wqkvb);
  fuse_bias_k<<<3, 256, 0, stream>>>(qbias, kbias, vbias, qkvbias, stats);
  transpose_x_k<<<dim3(32, 144, 2), 256, 0, stream>>>(x, xt);

  {  // conv1: ya = xt @ c1wb^T + b (rotated out). 144 m-tiles x 8 n-tiles.
    GemmAP p{};
    p.A = xt; p.B = c1wb; p.C = ya; p.bias = conv1b;
    p.sAr = 2048; p.sBr = 2048; p.sCr = 512;
    p.K = 2048; p.ntn = 8;
    gemm_async_k<1><<<1152, 256, 0, stream>>>(p);
  }

  for (int it = 0; it < 2; it++) {
    __bf16* tin = it ? yb : ya;
    {  // fused qkv projection. 144 m-tiles x 10 n-tiles.
      GemmAP p{};
      p.A = tin; p.B = wqkvb; p.C = qkv; p.bias = qkvbias;
      p.sAr = 512; p.sBr = 512; p.sCr = 640;
      p.K = 512; p.ntn = 10;
      gemm_async_k<0><<<1440, 256, 0, stream>>>(p);
    }
    cc_scores_k<<<dim3(192, 2), 384, 0, stream>>>(qkv, attnfH, attnfW);
    cc_softmax_k<<<4608, 256, 0, stream>>>(attnfH, attnfW, a_h, a_w);
    {  // agg1: per (b,w): tmp1[b][h][w][c] = sum_i a_h[h,i] * v[b,i,w,c]
      AggP p{};
      p.A = a_h; p.B = qkv + 128; p.C = tmp1;
      p.bB1 = (long long)9216 * 640; p.bB2 = 640; p.sBr = (long long)96 * 640;
      p.cB1 = (long long)9216 * 512; p.cB2 = 512; p.sCr = (long long)96 * 512;
      agg_k<0><<<dim3(4, 1, 192), 256, 0, stream>>>(p);
    }
    {  // agg2 + epilogue: per (b,h)
      AggP p{};
      p.A = a_w; p.B = qkv + 128;
      p.bB1 = (long long)9216 * 640; p.bB2 = (long long)96 * 640; p.sBr = 640;
      p.cB1 = (long long)9216 * 512; p.cB2 = (long long)96 * 512; p.sCr = 512;
      p.tmp = tmp1; p.res = tin; p.gma = gma;
      if (it == 0) {
        p.C = yb;
        agg_k<1><<<dim3(4, 1, 192), 256, 0, stream>>>(p);
      } else {
        p.C = padb;
        agg_k<2><<<dim3(4, 1, 192), 256, 0, stream>>>(p);
      }
    }
  }

  reorder_w_k<<<512, 256, 0, stream>>>(cow, wrot);
  border0_k<<<194, 256, 0, stream>>>(padb);
  conv3_gemm_k<<<768, 256, 0, stream>>>(padb, wrot, zb);
  gn_stats_k<<<256, 256, 0, stream>>>(zb, stats);
  gn_write_k<<<dim3(8, 96, 2), 256, 0, stream>>>(zb, stats, gng, gnb, out);
}

// Round 9
// 596.446 us; speedup vs baseline: 1.1623x; 1.0344x over previous
//
#include <hip/hip_runtime.h>
#include <hip/hip_bf16.h>

// CCAttention pipeline on MI355X. fp32 in/out, bf16 MFMA internal, NHWC.
// B=2, CIN=2048, CINT=512, CQK=64, H=W=96, S=9216, NG=32.
// R7: gn_stats 256-block linear+atomic. KEPT.
// REVERTED experiments: R8 vtrans (+14us), R9 agg remap (+15us), R10 explicit
// dbuf (+73us), R11 conv3 64x128 (+16us).
// R12 (KEPT, verified): conv3 96x128 tiles, grid 768 = exactly 3.0 blocks/CU:
// 105.7 -> 90.5us, MfmaUtil 35->41%. Rule: exact-integer blocks/CU + >=3.4
// MFMA:load intensity + unchanged HBM-operand multiplicity.
// R13 (resubmitted -- R8 bench was an infra failure, no data): same 96x128
// shape for gemm_async (conv1 + qkv). conv1: grid 768 (192m x 4n) = 3.0/CU,
// was 1152 = 4.5/CU @ intensity 2.67; A (xt, HBM) multiplicity drops 8->4.
// qkv: grid 960 (192m x 5n) = 3.75/CU, was 5.625/CU. acc[3][4], LDS 28KB,
// intensity 24 MFMA : 7 loads.

typedef __bf16 bf8_t __attribute__((ext_vector_type(8)));
typedef float f32x4 __attribute__((ext_vector_type(4)));

union I4B8 { int4 i; bf8_t b; };

typedef const __attribute__((address_space(1))) void as1_cvoid;
typedef __attribute__((address_space(3))) void as3_void;
__device__ __forceinline__ void gload16(const void* g, void* l) {
  __builtin_amdgcn_global_load_lds((as1_cvoid*)g, (as3_void*)l, 16, 0, 0);
}
__device__ __forceinline__ int rot8(int c, int key) { return (c + key) & 7; }

// ---------------------------------------------------------------- weight prep
__global__ __launch_bounds__(256) void cast_rot_k(const float* s, __bf16* d, int K8, int total8) {
  int idx = blockIdx.x * 256 + threadIdx.x;
  if (idx >= total8) return;
  int c8 = idx % K8, n = idx / K8;
  int pos = rot8(c8 & 7, n & 7);
  const float* sp = s + ((long long)n * K8 + c8) * 8;
  float4 a = *(const float4*)sp, b = *(const float4*)(sp + 4);
  I4B8 u;
  u.b[0] = (__bf16)a.x; u.b[1] = (__bf16)a.y; u.b[2] = (__bf16)a.z; u.b[3] = (__bf16)a.w;
  u.b[4] = (__bf16)b.x; u.b[5] = (__bf16)b.y; u.b[6] = (__bf16)b.z; u.b[7] = (__bf16)b.w;
  *(int4*)(d + ((long long)n * K8 + (c8 & ~7) + pos) * 8) = u.i;
}

__global__ __launch_bounds__(256) void wqkv_rot_k(const float* qw, const float* kw, const float* vw, __bf16* d) {
  int idx = blockIdx.x * 256 + threadIdx.x;  // 640*64
  if (idx >= 640 * 64) return;
  int c8 = idx & 63, n = idx >> 6;
  const float* src = (n < 64) ? qw + (long long)n * 512
                   : (n < 128) ? kw + (long long)(n - 64) * 512
                               : vw + (long long)(n - 128) * 512;
  int pos = rot8(c8 & 7, n & 7);
  const float* sp = src + c8 * 8;
  float4 a = *(const float4*)sp, b = *(const float4*)(sp + 4);
  I4B8 u;
  u.b[0] = (__bf16)a.x; u.b[1] = (__bf16)a.y; u.b[2] = (__bf16)a.z; u.b[3] = (__bf16)a.w;
  u.b[4] = (__bf16)b.x; u.b[5] = (__bf16)b.y; u.b[6] = (__bf16)b.z; u.b[7] = (__bf16)b.w;
  *(int4*)(d + ((long long)n * 64 + (c8 & ~7) + pos) * 8) = u.i;
}

// also zeroes the 128-float stats accumulator (consumed much later by gn)
__global__ __launch_bounds__(256) void fuse_bias_k(const float* qb, const float* kb, const float* vb,
                                                   float* d, float* stats) {
  int i = blockIdx.x * 256 + threadIdx.x;
  if (i < 128) stats[i] = 0.f;
  if (i >= 640) return;
  d[i] = (i < 64) ? qb[i] : (i < 128) ? kb[i - 64] : vb[i - 128];
}

// conv3 weights -> wr[o][dydx*512+c] rotated by o&7; coalesced via LDS.
__global__ __launch_bounds__(256) void reorder_w_k(const float* w, __bf16* wr) {
  __shared__ float ls[4608];
  int o = blockIdx.x;
  int t = threadIdx.x;
  const float* base = w + (long long)o * 4608;
#pragma unroll
  for (int i = 0; i < 18; i++) ls[t + i * 256] = base[t + i * 256];
  __syncthreads();
#pragma unroll
  for (int i = 0; i < 3; i++) {
    int q = t + i * 256;
    if (q >= 576) break;
    int k0 = q * 8;
    int dydx = k0 / 512, c0 = k0 & 511;
    I4B8 u;
#pragma unroll
    for (int j = 0; j < 8; j++) u.b[j] = (__bf16)ls[(c0 + j) * 9 + dydx];
    int pos = rot8((k0 >> 3) & 7, o & 7);
    *(int4*)(wr + (long long)o * 4608 + (k0 & ~63) + pos * 8) = u.i;
  }
}

// x f32 NCHW -> xt bf16 NHWC, rotated by pixel&7.
__global__ __launch_bounds__(256) void transpose_x_k(const float* x, __bf16* xt) {
  __shared__ __bf16 l[64 * 66];
  int c0 = blockIdx.x * 64, s0 = blockIdx.y * 64, b = blockIdx.z;
  int t = threadIdx.x;
#pragma unroll
  for (int i = 0; i < 2; i++) {
    int slot = t + i * 256;
    int cl = slot >> 3, sch = slot & 7;
    const float* src = x + ((long long)(b * 2048 + c0 + cl)) * 9216 + s0 + sch * 8;
    float4 a = *(const float4*)src, bb = *(const float4*)(src + 4);
    __bf16* dst = &l[cl * 66 + sch * 8];
    dst[0] = (__bf16)a.x; dst[1] = (__bf16)a.y; dst[2] = (__bf16)a.z; dst[3] = (__bf16)a.w;
    dst[4] = (__bf16)bb.x; dst[5] = (__bf16)bb.y; dst[6] = (__bf16)bb.z; dst[7] = (__bf16)bb.w;
  }
  __syncthreads();
#pragma unroll
  for (int i = 0; i < 2; i++) {
    int slot = t + i * 256;
    int sl = slot >> 3, cch = slot & 7;
    I4B8 u;
#pragma unroll
    for (int j = 0; j < 8; j++) u.b[j] = l[(cch * 8 + j) * 66 + sl];
    *(int4*)(xt + ((long long)(b * 9216 + s0 + sl)) * 2048 + c0 + rot8(cch, sl & 7) * 8) = u.i;
  }
}

// zero the padb border pixels (interior is written by agg2 it=1)
__global__ __launch_bounds__(256) void border0_k(__bf16* padb) {
  int idx = blockIdx.x * 256 + threadIdx.x;  // 776 border pixels * 64 int4
  if (idx >= 776 * 64) return;
  int ch = idx & 63, bi = idx >> 6;
  int b = bi / 388, r = bi % 388;
  int hh, ww;
  if (r < 98) { hh = 0; ww = r; }
  else if (r < 196) { hh = 97; ww = r - 98; }
  else if (r < 292) { hh = r - 196 + 1; ww = 0; }
  else { hh = r - 292 + 1; ww = 97; }
  *(int4*)(padb + ((long long)(b * 9604 + hh * 98 + ww)) * 512 + ch * 8) = make_int4(0, 0, 0, 0);
}

// ---------------------------------------------------------------- async GEMM
// R13: 96(M)x128(N) tiles, 4 waves in 2x2, wave tile 48x64, acc[3][4].
// LDS 28KB, intensity 24 MFMA : 7 loads per thread per K-step.
struct GemmAP {
  const __bf16 *A, *B;
  __bf16* C;
  const float* bias;
  long long sAr, sBr, sCr;
  int K, ntn;
};

template <int CROT>
__global__ __launch_bounds__(256) void gemm_async_k(GemmAP p) {
  __shared__ __attribute__((aligned(16))) __bf16 lA[96 * 64];
  __shared__ __attribute__((aligned(16))) __bf16 lB[128 * 64];
  const int t = threadIdx.x;
  const int id = blockIdx.x;
  const int per8 = gridDim.x >> 3;
  const int lin = (id & 7) * per8 + (id >> 3);
  const int m0 = (lin / p.ntn) * 96, n0 = (lin % p.ntn) * 128;
  const int lane = t & 63, wave = t >> 6;
  const int wm = (wave >> 1) * 48, wn = (wave & 1) * 64;
  const int l15 = lane & 15, l4 = lane >> 4;
  const int srow = (lane >> 3), schunk = (lane & 7) * 8;
  const int rbA = wave * 24, rbB = wave * 32;
  f32x4 acc[3][4];
#pragma unroll
  for (int i = 0; i < 3; i++)
#pragma unroll
    for (int j = 0; j < 4; j++) acc[i][j] = f32x4{0.f, 0.f, 0.f, 0.f};

  for (int kb = 0; kb < p.K; kb += 64) {
#pragma unroll
    for (int i = 0; i < 3; i++) {
      int row = rbA + i * 8;
      gload16(p.A + (long long)(m0 + row + srow) * p.sAr + kb + schunk, &lA[row * 64]);
    }
#pragma unroll
    for (int i = 0; i < 4; i++) {
      int row = rbB + i * 8;
      gload16(p.B + (long long)(n0 + row + srow) * p.sBr + kb + schunk, &lB[row * 64]);
    }
    __syncthreads();
#pragma unroll
    for (int kk = 0; kk < 2; kk++) {
      bf8_t af[3], bfr[4];
      int cch = kk * 4 + l4;
#pragma unroll
      for (int mt = 0; mt < 3; mt++) {
        int r = wm + mt * 16 + l15;
        af[mt] = *(bf8_t*)&lA[r * 64 + (rot8(cch, r & 7) << 3)];
      }
#pragma unroll
      for (int nt = 0; nt < 4; nt++) {
        int r = wn + nt * 16 + l15;
        bfr[nt] = *(bf8_t*)&lB[r * 64 + (rot8(cch, r & 7) << 3)];
      }
#pragma unroll
      for (int mt = 0; mt < 3; mt++)
#pragma unroll
        for (int nt = 0; nt < 4; nt++)
          acc[mt][nt] = __builtin_amdgcn_mfma_f32_16x16x32_bf16(af[mt], bfr[nt], acc[mt][nt], 0, 0, 0);
    }
    __syncthreads();
  }
#pragma unroll
  for (int nt = 0; nt < 4; nt++) {
    int col = n0 + wn + nt * 16 + l15;
    float bv = p.bias[col];
#pragma unroll
    for (int mt = 0; mt < 3; mt++) {
      int row0 = m0 + wm + mt * 16 + (l4 << 2);
#pragma unroll
      for (int r = 0; r < 4; r++) {
        int row = row0 + r;
        int pc = CROT ? (col & ~63) + (rot8((col >> 3) & 7, row & 7) << 3) + (col & 7) : col;
        p.C[(long long)row * p.sCr + pc] = (__bf16)(acc[mt][nt][r] + bv);
      }
    }
  }
}

// ---------------------------------------------------------------- agg GEMM
// Batched 96(M)x512(N)x128(Kpad) GEMM. A (a_h/a_w): rows pre-rotated (key
// row&7), padded K=128, batch stride 96*128 -> async staging. B: V section
// of qkv, transposed-in-LDS (k rows, guard k<96 -> zeros).  [R2 staging]
// MODE 0: C=acc (tmp1). MODE 1: C[rot]=g*(tmp+acc)+res. MODE 2: same but
// store into padb at (h+1,w+1) with key (w+1)&7.
struct AggP {
  const __bf16 *A, *B;  // B = qkv + 128 (V columns)
  __bf16* C;
  const __bf16 *tmp, *res;
  const float* gma;
  long long bB1, bB2, sBr;
  long long cB1, cB2, sCr;
};

template <int MODE>
__global__ __launch_bounds__(256) void agg_k(AggP p) {
  __shared__ __attribute__((aligned(16))) __bf16 lA[128 * 64];
  __shared__ __attribute__((aligned(16))) __bf16 lB[128 * 64];
  const int t = threadIdx.x;
  const int z = blockIdx.z;
  const int z1 = z / 96, z2 = z % 96;
  const __bf16* A = p.A + (long long)z * (96 * 128);
  const __bf16* B = p.B + (long long)z1 * p.bB1 + (long long)z2 * p.bB2;
  const int n0 = blockIdx.x * 128;
  const int lane = t & 63, wave = t >> 6;
  const int wm = (wave >> 1) * 64, wn = (wave & 1) * 64;
  const int l15 = lane & 15, l4 = lane >> 4;
  const int srow = lane >> 3, schunk = (lane & 7) * 8;
  f32x4 acc[4][4];
#pragma unroll
  for (int i = 0; i < 4; i++)
#pragma unroll
    for (int j = 0; j < 4; j++) acc[i][j] = f32x4{0.f, 0.f, 0.f, 0.f};

#pragma unroll
  for (int kb = 0; kb < 128; kb += 64) {
    const int rb = wave * 32;
#pragma unroll
    for (int i = 0; i < 4; i++) {
      int row = rb + i * 8;
      gload16(A + (long long)(row + srow) * 128 + kb + schunk, &lA[row * 64]);
    }
#pragma unroll
    for (int i = 0; i < 4; i++) {
      int slot = t + i * 256;
      int kl = slot & 63, cch = slot >> 6;
      int gk = kb + kl;
      I4B8 u;
      u.i = make_int4(0, 0, 0, 0);
      if (gk < 96) u.i = *(const int4*)(B + (long long)gk * p.sBr + n0 + cch * 8);
#pragma unroll
      for (int j = 0; j < 8; j++) {
        int n = cch * 8 + j;
        lB[n * 64 + (rot8(kl >> 3, n & 7) << 3) + (kl & 7)] = u.b[j];
      }
    }
    __syncthreads();
#pragma unroll
    for (int kk = 0; kk < 2; kk++) {
      bf8_t af[4], bfr[4];
      int cch = kk * 4 + l4;
#pragma unroll
      for (int mt = 0; mt < 4; mt++) {
        int r = wm + mt * 16 + l15;
        af[mt] = *(bf8_t*)&lA[r * 64 + (rot8(cch, r & 7) << 3)];
      }
#pragma unroll
      for (int nt = 0; nt < 4; nt++) {
        int r = wn + nt * 16 + l15;
        bfr[nt] = *(bf8_t*)&lB[r * 64 + (rot8(cch, r & 7) << 3)];
      }
#pragma unroll
      for (int mt = 0; mt < 4; mt++)
#pragma unroll
        for (int nt = 0; nt < 4; nt++)
          acc[mt][nt] = __builtin_amdgcn_mfma_f32_16x16x32_bf16(af[mt], bfr[nt], acc[mt][nt], 0, 0, 0);
    }
    __syncthreads();
  }
  long long cbase = (long long)z1 * p.cB1 + (long long)z2 * p.cB2;
  float g = MODE ? *p.gma : 0.f;
#pragma unroll
  for (int nt = 0; nt < 4; nt++) {
    int col = n0 + wn + nt * 16 + l15;
#pragma unroll
    for (int mt = 0; mt < 4; mt++) {
      int row0 = wm + mt * 16 + (l4 << 2);
#pragma unroll
      for (int r = 0; r < 4; r++) {
        int row = row0 + r;
        if (row >= 96) continue;
        long long offL = cbase + (long long)row * p.sCr + col;
        float v = acc[mt][nt][r];
        if (MODE == 0) {
          p.C[offL] = (__bf16)v;
        } else {
          int rc = (col & ~63) + (rot8((col >> 3) & 7, row & 7) << 3) + (col & 7);
          long long offP = cbase + (long long)row * p.sCr + rc;
          v = g * ((float)p.tmp[offL] + v) + (float)p.res[offP];
          if (MODE == 1) {
            p.C[offP] = (__bf16)v;
          } else {
            int pc = (col & ~63) + (rot8((col >> 3) & 7, (row + 1) & 7) << 3) + (col & 7);
            long long pidx = (long long)z1 * 9604 + (long long)(z2 + 1) * 98 + (row + 1);
            p.C[pidx * 512 + pc] = (__bf16)v;
          }
        }
      }
    }
  }
}

// ---------------------------------------------------------------- scores
// mode 0 (b,w): E[h][i] (diag -inf) -> attnfH[b*96+w][h*96+i]
// mode 1 (b,h): E[w][j]             -> attnfW[b*96+h][w*96+j]
__global__ __launch_bounds__(384) void cc_scores_k(const __bf16* qkv, float* attnfH, float* attnfW) {
  __shared__ __attribute__((aligned(16))) __bf16 Qs[96 * 64];
  __shared__ __attribute__((aligned(16))) __bf16 Ks[96 * 64];
  int bfi = blockIdx.x;
  int b = bfi / 96, f = bfi % 96;
  int mode = blockIdx.y;
  long long base = (mode == 0) ? ((long long)(b * 9216 + f)) * 640 : ((long long)(b * 9216 + f * 96)) * 640;
  long long rstr = (mode == 0) ? 96 * 640 : 640;
  int t = threadIdx.x;
#pragma unroll
  for (int i = 0; i < 2; i++) {
    int slot = t + i * 384;
    int r = slot >> 3, c = slot & 7;
    int sw = rot8(c, r & 7) << 3;
    *(int4*)&Qs[r * 64 + sw] = *(const int4*)(qkv + base + (long long)r * rstr + c * 8);
    *(int4*)&Ks[r * 64 + sw] = *(const int4*)(qkv + base + (long long)r * rstr + 64 + c * 8);
  }
  __syncthreads();
  int lane = t & 63, wave = t >> 6;
  int l15 = lane & 15, l4 = lane >> 4;
  f32x4 acc[6];
#pragma unroll
  for (int i = 0; i < 6; i++) acc[i] = f32x4{0.f, 0.f, 0.f, 0.f};
#pragma unroll
  for (int kk = 0; kk < 2; kk++) {
    int ar = wave * 16 + l15;
    int cch = kk * 4 + l4;
    bf8_t af = *(bf8_t*)&Qs[ar * 64 + (rot8(cch, ar & 7) << 3)];
#pragma unroll
    for (int nt = 0; nt < 6; nt++) {
      int br = nt * 16 + l15;
      bf8_t bfr = *(bf8_t*)&Ks[br * 64 + (rot8(cch, br & 7) << 3)];
      acc[nt] = __builtin_amdgcn_mfma_f32_16x16x32_bf16(af, bfr, acc[nt], 0, 0, 0);
    }
  }
  float* dst = (mode == 0 ? attnfH : attnfW) + (long long)bfi * 9216;
#pragma unroll
  for (int nt = 0; nt < 6; nt++) {
#pragma unroll
    for (int r = 0; r < 4; r++) {
      int m = wave * 16 + (l4 << 2) + r;
      int n = nt * 16 + l15;
      float v = acc[nt][r];
      if (mode == 0 && n == m) v = -__builtin_inff();
      dst[m * 96 + n] = v;
    }
  }
}

// softmax over concat[e_h, e_w] (192), writes padded+rotated a_h/a_w rows.
__global__ __launch_bounds__(256) void cc_softmax_k(const float* attnfH, const float* attnfW,
                                                    __bf16* a_h, __bf16* a_w) {
  int wave = threadIdx.x >> 6, lane = threadIdx.x & 63;
  int pix = blockIdx.x * 4 + wave;
  int b = pix / 9216, hw = pix % 9216;
  int h = hw / 96, w2 = hw % 96;
  const float* ehb = attnfH + ((long long)(b * 96 + w2)) * 9216 + h * 96;
  const float* ewb = attnfW + ((long long)(b * 96 + h)) * 9216 + w2 * 96;
  float x0 = ehb[lane];
  float x1 = lane < 32 ? ehb[64 + lane] : -__builtin_inff();
  float x2 = ewb[lane];
  float x3 = lane < 32 ? ewb[64 + lane] : -__builtin_inff();
  float m = fmaxf(fmaxf(x0, x1), fmaxf(x2, x3));
#pragma unroll
  for (int o = 32; o; o >>= 1) m = fmaxf(m, __shfl_xor(m, o));
  float e0 = __expf(x0 - m), e1 = __expf(x1 - m), e2 = __expf(x2 - m), e3 = __expf(x3 - m);
  float s = e0 + e1 + e2 + e3;
#pragma unroll
  for (int o = 32; o; o >>= 1) s += __shfl_xor(s, o);
  float inv = 1.f / s;
  // a_h row (h), key h&7 ; a_w row (w2), key w2&7
  __bf16* dh = a_h + ((long long)((b * 96 + w2) * 96 + h)) * 128;
  __bf16* dw = a_w + ((long long)((b * 96 + h) * 96 + w2)) * 128;
  int kh = h & 7, kw2 = w2 & 7;
  int k1 = lane, k2 = 64 + lane;
  int p1h = (k1 & ~63) + (rot8((k1 >> 3) & 7, kh) << 3) + (k1 & 7);
  int p2h = (k2 & ~63) + (rot8((k2 >> 3) & 7, kh) << 3) + (k2 & 7);
  int p1w = (k1 & ~63) + (rot8((k1 >> 3) & 7, kw2) << 3) + (k1 & 7);
  int p2w = (k2 & ~63) + (rot8((k2 >> 3) & 7, kw2) << 3) + (k2 & 7);
  dh[p1h] = (__bf16)(e0 * inv);
  dh[p2h] = (__bf16)(lane < 32 ? e1 * inv : 0.f);
  dw[p1w] = (__bf16)(e2 * inv);
  dw[p2w] = (__bf16)(lane < 32 ? e3 * inv : 0.f);
}

// ---------------------------------------------------------------- conv3x3
// R12: 96(M)x128(N) tiles, grid 768 (192m x 4n) = exactly 3 blocks/CU.
// 4 waves in 2x2, wave tile 48x64, acc[3][4]. LDS 28KB. Single-buffered
// 2-barrier K-loop (proven structure).
__global__ __launch_bounds__(256) void conv3_gemm_k(const __bf16* pin, const __bf16* wr, __bf16* C) {
  __shared__ __attribute__((aligned(16))) __bf16 lA[96 * 64];
  __shared__ __attribute__((aligned(16))) __bf16 lB[128 * 64];
  const int t = threadIdx.x;
  const int id = blockIdx.x;
  const int per8 = gridDim.x >> 3;                 // 96
  const int lin = (id & 7) * per8 + (id >> 3);
  const int m0 = (lin >> 2) * 96, n0 = (lin & 3) * 128;
  const int lane = t & 63, wave = t >> 6;
  const int wm = (wave >> 1) * 48, wn = (wave & 1) * 64;
  const int l15 = lane & 15, l4 = lane >> 4;
  const int srow = lane >> 3, schunk = (lane & 7) * 8;
  const int rbA = wave * 24, rbB = wave * 32;
  f32x4 acc[3][4];
#pragma unroll
  for (int i = 0; i < 3; i++)
#pragma unroll
    for (int j = 0; j < 4; j++) acc[i][j] = f32x4{0.f, 0.f, 0.f, 0.f};
  long long sbase[3], bbase[4];
#pragma unroll
  for (int i = 0; i < 3; i++) {
    int r = rbA + i * 8 + srow;
    int m = m0 + r;
    int b = m / 9216, hw = m % 9216;
    int h = hw / 96, w2 = hw % 96;
    sbase[i] = ((long long)b * 9604 + h * 98 + w2) * 512 + schunk;
  }
#pragma unroll
  for (int i = 0; i < 4; i++) {
    int r = rbB + i * 8 + srow;
    bbase[i] = (long long)(n0 + r) * 4608 + schunk;
  }
  int w2f[3];
#pragma unroll
  for (int mt = 0; mt < 3; mt++) w2f[mt] = (m0 + wm + mt * 16 + l15) % 96;

  int kt = 0;
  for (int tap = 0; tap < 9; tap++) {
    const int dy = tap / 3, dx = tap - dy * 3;
    const long long aoff = (long long)(dy * 98 + dx) * 512;
    int keyA[3];
#pragma unroll
    for (int mt = 0; mt < 3; mt++) keyA[mt] = (w2f[mt] + dx) & 7;
    for (int sl = 0; sl < 8; sl++, kt++) {
      const int c0k = sl * 64;
#pragma unroll
      for (int i = 0; i < 3; i++)
        gload16(pin + sbase[i] + aoff + c0k, &lA[(rbA + i * 8) * 64]);
#pragma unroll
      for (int i = 0; i < 4; i++)
        gload16(wr + bbase[i] + kt * 64, &lB[(rbB + i * 8) * 64]);
      __syncthreads();
#pragma unroll
      for (int kk = 0; kk < 2; kk++) {
        bf8_t af[3], bfr[4];
        int cch = kk * 4 + l4;
#pragma unroll
        for (int mt = 0; mt < 3; mt++) {
          int r = wm + mt * 16 + l15;
          af[mt] = *(bf8_t*)&lA[r * 64 + (rot8(cch, keyA[mt]) << 3)];
        }
#pragma unroll
        for (int nt = 0; nt < 4; nt++) {
          int r = wn + nt * 16 + l15;
          bfr[nt] = *(bf8_t*)&lB[r * 64 + (rot8(cch, r & 7) << 3)];
        }
#pragma unroll
        for (int mt = 0; mt < 3; mt++)
#pragma unroll
          for (int nt = 0; nt < 4; nt++)
            acc[mt][nt] = __builtin_amdgcn_mfma_f32_16x16x32_bf16(af[mt], bfr[nt], acc[mt][nt], 0, 0, 0);
      }
      __syncthreads();
    }
  }
#pragma unroll
  for (int nt = 0; nt < 4; nt++) {
    int col = n0 + wn + nt * 16 + l15;
#pragma unroll
    for (int mt = 0; mt < 3; mt++) {
      int row0 = m0 + wm + mt * 16 + (l4 << 2);
#pragma unroll
      for (int r = 0; r < 4; r++) {
        int row = row0 + r;
        C[(long long)row * 512 + col] = (__bf16)acc[mt][nt][r];
      }
    }
  }
}

// ---------------------------------------------------------------- GroupNorm
// 256 blocks (1/CU), fully linear coalesced int4 reads; atomicAdd partials.
__global__ __launch_bounds__(256) void gn_stats_k(const __bf16* z, float* stats) {
  int bi = blockIdx.x, t = threadIdx.x;
  const __bf16* base = z + (long long)bi * (72 * 512);
  int g = (t & 63) >> 1;  // channel octet (t&63)*8 -> group
  float s = 0.f, ss = 0.f;
#pragma unroll
  for (int i = 0; i < 18; i++) {
    I4B8 u;
    u.i = *(const int4*)(base + ((long long)(t + i * 256)) * 8);
#pragma unroll
    for (int j = 0; j < 8; j++) {
      float f = (float)u.b[j];
      s += f;
      ss += f * f;
    }
  }
  s += __shfl_xor(s, 1);
  ss += __shfl_xor(ss, 1);
  __shared__ float red[2][4][32];
  int wave = t >> 6, lane = t & 63;
  if (!(lane & 1)) {
    red[0][wave][g] = s;
    red[1][wave][g] = ss;
  }
  __syncthreads();
  if (t < 32) {
    float S = red[0][0][t] + red[0][1][t] + red[0][2][t] + red[0][3][t];
    float SS = red[1][0][t] + red[1][1][t] + red[1][2][t] + red[1][3][t];
    int b = bi >> 7;  // 128 blocks per batch (72*128 = 9216 px)
    atomicAdd(&stats[2 * (b * 32 + t)], S);
    atomicAdd(&stats[2 * (b * 32 + t) + 1], SS);
  }
}

__global__ __launch_bounds__(256) void gn_write_k(const __bf16* z, const float* stats,
                                                 const float* gng, const float* gnb, float* out) {
  __shared__ __bf16 l[64 * 98];
  int c0 = blockIdx.x * 64, h = blockIdx.y, b = blockIdx.z;
  int t = threadIdx.x;
#pragma unroll
  for (int i = 0; i < 3; i++) {
    int slot = t + i * 256;
    int wl = slot >> 3, cch = slot & 7;
    I4B8 u;
    u.i = *(const int4*)(z + ((long long)(b * 9216 + h * 96 + wl)) * 512 + c0 + cch * 8);
#pragma unroll
    for (int j = 0; j < 8; j++) l[(cch * 8 + j) * 98 + wl] = u.b[j];
  }
  __syncthreads();
  const float inv = 1.f / 147456.f;
#pragma unroll
  for (int i = 0; i < 3; i++) {
    int slot = t + i * 256;
    int wch = slot % 12, cl = slot / 12;
    int c = c0 + cl;
    int g = c >> 4;
    float S = stats[2 * (b * 32 + g)], SS = stats[2 * (b * 32 + g) + 1];
    float mean = S * inv;
    float rstd = rsqrtf(SS * inv - mean * mean + 1e-5f);
    float sc = rstd * gng[c];
    float sh = gnb[c] - mean * sc;
    float4 o0, o1;
    const __bf16* src = &l[cl * 98 + wch * 8];
    o0.x = (float)src[0] * sc + sh; o0.y = (float)src[1] * sc + sh;
    o0.z = (float)src[2] * sc + sh; o0.w = (float)src[3] * sc + sh;
    o1.x = (float)src[4] * sc + sh; o1.y = (float)src[5] * sc + sh;
    o1.z = (float)src[6] * sc + sh; o1.w = (float)src[7] * sc + sh;
    float* dst = out + ((long long)((b * 512 + c) * 96 + h)) * 96 + wch * 8;
    *(float4*)dst = o0;
    *(float4*)(dst + 4) = o1;
  }
}

// ---------------------------------------------------------------- launch
extern "C" void kernel_launch(void* const* d_in, const int* in_sizes, int n_in,
                              void* d_out, int out_size, void* d_ws, size_t ws_size,
                              hipStream_t stream) {
  (void)in_sizes; (void)n_in; (void)out_size;
  const float* x = (const float*)d_in[0];
  const float* conv1w = (const float*)d_in[1];
  const float* conv1b = (const float*)d_in[2];
  const float* qw = (const float*)d_in[3];
  const float* qbias = (const float*)d_in[4];
  const float* kw = (const float*)d_in[5];
  const float* kbias = (const float*)d_in[6];
  const float* vw = (const float*)d_in[7];
  const float* vbias = (const float*)d_in[8];
  const float* gma = (const float*)d_in[9];
  const float* cow = (const float*)d_in[10];
  const float* gng = (const float*)d_in[11];
  const float* gnb = (const float*)d_in[12];
  float* out = (float*)d_out;

  if (ws_size < 134876160ULL) return;

  char* w = (char*)d_ws;
  __bf16* xt     = (__bf16*)(w);                 // 75,497,472 (phase 1)
  __bf16* qkv    = (__bf16*)(w);                 // 23,592,960
  float* attnfH  = (float*)(w + 23592960);       // 7,077,888
  float* attnfW  = (float*)(w + 30670848);       // 7,077,888
  __bf16* a_h    = (__bf16*)(w + 37748736);      // 4,718,592
  __bf16* a_w    = (__bf16*)(w + 42467328);      // 4,718,592
  __bf16* padb   = (__bf16*)(w + 47185920);      // 19,668,992
  __bf16* wrot   = (__bf16*)(w + 66854912);      // 4,718,592
  __bf16* ya     = (__bf16*)(w + 75497472);      // 18,874,368
  __bf16* yb     = (__bf16*)(w + 94371840);      // 18,874,368
  __bf16* tmp1   = (__bf16*)(w + 113246208);     // 18,874,368
  __bf16* zb     = (__bf16*)(w);                 // 18,874,368 (after attention)
  __bf16* c1wb   = (__bf16*)(w + 132120576);     // 2,097,152
  __bf16* wqkvb  = (__bf16*)(w + 134217728);     // 655,360
  float* qkvbias = (float*)(w + 134873088);      // 2,560
  float* stats   = (float*)(w + 134875648);      // 512

  cast_rot_k<<<512, 256, 0, stream>>>(conv1w, c1wb, 256, 131072);
  wqkv_rot_k<<<160, 256, 0, stream>>>(qw, kw, vw, wqkvb);
  fuse_bias_k<<<3, 256, 0, stream>>>(qbias, kbias, vbias, qkvbias, stats);
  transpose_x_k<<<dim3(32, 144, 2), 256, 0, stream>>>(x, xt);

  {  // conv1: ya = xt @ c1wb^T + b (rotated out). 192 m-tiles x 4 n-tiles.
    GemmAP p{};
    p.A = xt; p.B = c1wb; p.C = ya; p.bias = conv1b;
    p.sAr = 2048; p.sBr = 2048; p.sCr = 512;
    p.K = 2048; p.ntn = 4;
    gemm_async_k<1><<<768, 256, 0, stream>>>(p);
  }

  for (int it = 0; it < 2; it++) {
    __bf16* tin = it ? yb : ya;
    {  // fused qkv projection. 192 m-tiles x 5 n-tiles.
      GemmAP p{};
      p.A = tin; p.B = wqkvb; p.C = qkv; p.bias = qkvbias;
      p.sAr = 512; p.sBr = 512; p.sCr = 640;
      p.K = 512; p.ntn = 5;
      gemm_async_k<0><<<960, 256, 0, stream>>>(p);
    }
    cc_scores_k<<<dim3(192, 2), 384, 0, stream>>>(qkv, attnfH, attnfW);
    cc_softmax_k<<<4608, 256, 0, stream>>>(attnfH, attnfW, a_h, a_w);
    {  // agg1: per (b,w): tmp1[b][h][w][c] = sum_i a_h[h,i] * v[b,i,w,c]
      AggP p{};
      p.A = a_h; p.B = qkv + 128; p.C = tmp1;
      p.bB1 = (long long)9216 * 640; p.bB2 = 640; p.sBr = (long long)96 * 640;
      p.cB1 = (long long)9216 * 512; p.cB2 = 512; p.sCr = (long long)96 * 512;
      agg_k<0><<<dim3(4, 1, 192), 256, 0, stream>>>(p);
    }
    {  // agg2 + epilogue: per (b,h)
      AggP p{};
      p.A = a_w; p.B = qkv + 128;
      p.bB1 = (long long)9216 * 640; p.bB2 = (long long)96 * 640; p.sBr = 640;
      p.cB1 = (long long)9216 * 512; p.cB2 = (long long)96 * 512; p.sCr = 512;
      p.tmp = tmp1; p.res = tin; p.gma = gma;
      if (it == 0) {
        p.C = yb;
        agg_k<1><<<dim3(4, 1, 192), 256, 0, stream>>>(p);
      } else {
        p.C = padb;
        agg_k<2><<<dim3(4, 1, 192), 256, 0, stream>>>(p);
      }
    }
  }

  reorder_w_k<<<512, 256, 0, stream>>>(cow, wrot);
  border0_k<<<194, 256, 0, stream>>>(padb);
  conv3_gemm_k<<<768, 256, 0, stream>>>(padb, wrot, zb);
  gn_stats_k<<<256, 256, 0, stream>>>(zb, stats);
  gn_write_k<<<dim3(8, 96, 2), 256, 0, stream>>>(zb, stats, gng, gnb, out);
}

// Round 10
// 569.385 us; speedup vs baseline: 1.2175x; 1.0475x over previous
//
#include <hip/hip_runtime.h>
#include <hip/hip_bf16.h>

// CCAttention pipeline on MI355X. fp32 in/out, bf16 MFMA internal, NHWC.
// B=2, CIN=2048, CINT=512, CQK=64, H=W=96, S=9216, NG=32.
// REVERTED experiments: R8 vtrans (+14us), R9 agg remap (+15us), R10 explicit
// dbuf (+73us), R11 conv3 64x128 (+16us).
// R12/R13 (KEPT, verified): 96x128 tiles, grid 768 = exactly 3.0 blocks/CU
// for conv3 (105.7->90.5us) and conv1 (~-15us). Rule: exact-integer blocks/CU
// + >=3.4 MFMA:load intensity + unchanged HBM-operand multiplicity.
// R14: (a) qkv tiles 96x160 (NT=5), grid 768 = 3.0/CU exact (was 960 =
// 3.75/CU with 75%-fill tail), intensity 30:8. (b) gn_stats fused into
// conv3 epilogue (f32 partials + shfl reduce + 16 atomicAdd/block; removes
// an 18.9MB re-read dispatch). (c) agg grid (192,1,4): B-sharing blocks
// land on same XCD (ids differ by 192 = 0 mod 8) for L2 reuse.

typedef __bf16 bf8_t __attribute__((ext_vector_type(8)));
typedef float f32x4 __attribute__((ext_vector_type(4)));

union I4B8 { int4 i; bf8_t b; };

typedef const __attribute__((address_space(1))) void as1_cvoid;
typedef __attribute__((address_space(3))) void as3_void;
__device__ __forceinline__ void gload16(const void* g, void* l) {
  __builtin_amdgcn_global_load_lds((as1_cvoid*)g, (as3_void*)l, 16, 0, 0);
}
__device__ __forceinline__ int rot8(int c, int key) { return (c + key) & 7; }

// ---------------------------------------------------------------- weight prep
__global__ __launch_bounds__(256) void cast_rot_k(const float* s, __bf16* d, int K8, int total8) {
  int idx = blockIdx.x * 256 + threadIdx.x;
  if (idx >= total8) return;
  int c8 = idx % K8, n = idx / K8;
  int pos = rot8(c8 & 7, n & 7);
  const float* sp = s + ((long long)n * K8 + c8) * 8;
  float4 a = *(const float4*)sp, b = *(const float4*)(sp + 4);
  I4B8 u;
  u.b[0] = (__bf16)a.x; u.b[1] = (__bf16)a.y; u.b[2] = (__bf16)a.z; u.b[3] = (__bf16)a.w;
  u.b[4] = (__bf16)b.x; u.b[5] = (__bf16)b.y; u.b[6] = (__bf16)b.z; u.b[7] = (__bf16)b.w;
  *(int4*)(d + ((long long)n * K8 + (c8 & ~7) + pos) * 8) = u.i;
}

__global__ __launch_bounds__(256) void wqkv_rot_k(const float* qw, const float* kw, const float* vw, __bf16* d) {
  int idx = blockIdx.x * 256 + threadIdx.x;  // 640*64
  if (idx >= 640 * 64) return;
  int c8 = idx & 63, n = idx >> 6;
  const float* src = (n < 64) ? qw + (long long)n * 512
                   : (n < 128) ? kw + (long long)(n - 64) * 512
                               : vw + (long long)(n - 128) * 512;
  int pos = rot8(c8 & 7, n & 7);
  const float* sp = src + c8 * 8;
  float4 a = *(const float4*)sp, b = *(const float4*)(sp + 4);
  I4B8 u;
  u.b[0] = (__bf16)a.x; u.b[1] = (__bf16)a.y; u.b[2] = (__bf16)a.z; u.b[3] = (__bf16)a.w;
  u.b[4] = (__bf16)b.x; u.b[5] = (__bf16)b.y; u.b[6] = (__bf16)b.z; u.b[7] = (__bf16)b.w;
  *(int4*)(d + ((long long)n * 64 + (c8 & ~7) + pos) * 8) = u.i;
}

// also zeroes the 128-float stats accumulator (consumed much later by gn)
__global__ __launch_bounds__(256) void fuse_bias_k(const float* qb, const float* kb, const float* vb,
                                                   float* d, float* stats) {
  int i = blockIdx.x * 256 + threadIdx.x;
  if (i < 128) stats[i] = 0.f;
  if (i >= 640) return;
  d[i] = (i < 64) ? qb[i] : (i < 128) ? kb[i - 64] : vb[i - 128];
}

// conv3 weights -> wr[o][dydx*512+c] rotated by o&7; coalesced via LDS.
__global__ __launch_bounds__(256) void reorder_w_k(const float* w, __bf16* wr) {
  __shared__ float ls[4608];
  int o = blockIdx.x;
  int t = threadIdx.x;
  const float* base = w + (long long)o * 4608;
#pragma unroll
  for (int i = 0; i < 18; i++) ls[t + i * 256] = base[t + i * 256];
  __syncthreads();
#pragma unroll
  for (int i = 0; i < 3; i++) {
    int q = t + i * 256;
    if (q >= 576) break;
    int k0 = q * 8;
    int dydx = k0 / 512, c0 = k0 & 511;
    I4B8 u;
#pragma unroll
    for (int j = 0; j < 8; j++) u.b[j] = (__bf16)ls[(c0 + j) * 9 + dydx];
    int pos = rot8((k0 >> 3) & 7, o & 7);
    *(int4*)(wr + (long long)o * 4608 + (k0 & ~63) + pos * 8) = u.i;
  }
}

// x f32 NCHW -> xt bf16 NHWC, rotated by pixel&7.
__global__ __launch_bounds__(256) void transpose_x_k(const float* x, __bf16* xt) {
  __shared__ __bf16 l[64 * 66];
  int c0 = blockIdx.x * 64, s0 = blockIdx.y * 64, b = blockIdx.z;
  int t = threadIdx.x;
#pragma unroll
  for (int i = 0; i < 2; i++) {
    int slot = t + i * 256;
    int cl = slot >> 3, sch = slot & 7;
    const float* src = x + ((long long)(b * 2048 + c0 + cl)) * 9216 + s0 + sch * 8;
    float4 a = *(const float4*)src, bb = *(const float4*)(src + 4);
    __bf16* dst = &l[cl * 66 + sch * 8];
    dst[0] = (__bf16)a.x; dst[1] = (__bf16)a.y; dst[2] = (__bf16)a.z; dst[3] = (__bf16)a.w;
    dst[4] = (__bf16)bb.x; dst[5] = (__bf16)bb.y; dst[6] = (__bf16)bb.z; dst[7] = (__bf16)bb.w;
  }
  __syncthreads();
#pragma unroll
  for (int i = 0; i < 2; i++) {
    int slot = t + i * 256;
    int sl = slot >> 3, cch = slot & 7;
    I4B8 u;
#pragma unroll
    for (int j = 0; j < 8; j++) u.b[j] = l[(cch * 8 + j) * 66 + sl];
    *(int4*)(xt + ((long long)(b * 9216 + s0 + sl)) * 2048 + c0 + rot8(cch, sl & 7) * 8) = u.i;
  }
}

// zero the padb border pixels (interior is written by agg2 it=1)
__global__ __launch_bounds__(256) void border0_k(__bf16* padb) {
  int idx = blockIdx.x * 256 + threadIdx.x;  // 776 border pixels * 64 int4
  if (idx >= 776 * 64) return;
  int ch = idx & 63, bi = idx >> 6;
  int b = bi / 388, r = bi % 388;
  int hh, ww;
  if (r < 98) { hh = 0; ww = r; }
  else if (r < 196) { hh = 97; ww = r - 98; }
  else if (r < 292) { hh = r - 196 + 1; ww = 0; }
  else { hh = r - 292 + 1; ww = 97; }
  *(int4*)(padb + ((long long)(b * 9604 + hh * 98 + ww)) * 512 + ch * 8) = make_int4(0, 0, 0, 0);
}

// ---------------------------------------------------------------- async GEMM
// 96(M) x NT*32(N) tiles, 4 waves in 2x2, wave tile 48 x NT*16, acc[3][NT].
// NT=4: conv1 (128 N, LDS 28KB). NT=5: qkv (160 N, LDS 32KB).
struct GemmAP {
  const __bf16 *A, *B;
  __bf16* C;
  const float* bias;
  long long sAr, sBr, sCr;
  int K, ntn;
};

template <int CROT, int NT>
__global__ __launch_bounds__(256) void gemm_async_k(GemmAP p) {
  __shared__ __attribute__((aligned(16))) __bf16 lA[96 * 64];
  __shared__ __attribute__((aligned(16))) __bf16 lB[NT * 32 * 64];
  const int t = threadIdx.x;
  const int id = blockIdx.x;
  const int per8 = gridDim.x >> 3;
  const int lin = (id & 7) * per8 + (id >> 3);
  const int m0 = (lin / p.ntn) * 96, n0 = (lin % p.ntn) * (NT * 32);
  const int lane = t & 63, wave = t >> 6;
  const int wm = (wave >> 1) * 48, wn = (wave & 1) * (NT * 16);
  const int l15 = lane & 15, l4 = lane >> 4;
  const int srow = (lane >> 3), schunk = (lane & 7) * 8;
  const int rbA = wave * 24, rbB = wave * (NT * 8);
  f32x4 acc[3][NT];
#pragma unroll
  for (int i = 0; i < 3; i++)
#pragma unroll
    for (int j = 0; j < NT; j++) acc[i][j] = f32x4{0.f, 0.f, 0.f, 0.f};

  for (int kb = 0; kb < p.K; kb += 64) {
#pragma unroll
    for (int i = 0; i < 3; i++) {
      int row = rbA + i * 8;
      gload16(p.A + (long long)(m0 + row + srow) * p.sAr + kb + schunk, &lA[row * 64]);
    }
#pragma unroll
    for (int i = 0; i < NT; i++) {
      int row = rbB + i * 8;
      gload16(p.B + (long long)(n0 + row + srow) * p.sBr + kb + schunk, &lB[row * 64]);
    }
    __syncthreads();
#pragma unroll
    for (int kk = 0; kk < 2; kk++) {
      bf8_t af[3], bfr[NT];
      int cch = kk * 4 + l4;
#pragma unroll
      for (int mt = 0; mt < 3; mt++) {
        int r = wm + mt * 16 + l15;
        af[mt] = *(bf8_t*)&lA[r * 64 + (rot8(cch, r & 7) << 3)];
      }
#pragma unroll
      for (int nt = 0; nt < NT; nt++) {
        int r = wn + nt * 16 + l15;
        bfr[nt] = *(bf8_t*)&lB[r * 64 + (rot8(cch, r & 7) << 3)];
      }
#pragma unroll
      for (int mt = 0; mt < 3; mt++)
#pragma unroll
        for (int nt = 0; nt < NT; nt++)
          acc[mt][nt] = __builtin_amdgcn_mfma_f32_16x16x32_bf16(af[mt], bfr[nt], acc[mt][nt], 0, 0, 0);
    }
    __syncthreads();
  }
#pragma unroll
  for (int nt = 0; nt < NT; nt++) {
    int col = n0 + wn + nt * 16 + l15;
    float bv = p.bias[col];
#pragma unroll
    for (int mt = 0; mt < 3; mt++) {
      int row0 = m0 + wm + mt * 16 + (l4 << 2);
#pragma unroll
      for (int r = 0; r < 4; r++) {
        int row = row0 + r;
        int pc = CROT ? (col & ~63) + (rot8((col >> 3) & 7, row & 7) << 3) + (col & 7) : col;
        p.C[(long long)row * p.sCr + pc] = (__bf16)(acc[mt][nt][r] + bv);
      }
    }
  }
}

// ---------------------------------------------------------------- agg GEMM
// Batched 96(M)x512(N)x128(Kpad) GEMM. A (a_h/a_w): rows pre-rotated (key
// row&7), padded K=128, batch stride 96*128 -> async staging. B: V section
// of qkv, transposed-in-LDS (k rows, guard k<96 -> zeros).  [R2 staging]
// R14: z on blockIdx.x, n-tile on blockIdx.z -> B-sharing blocks same-XCD.
// MODE 0: C=acc (tmp1). MODE 1: C[rot]=g*(tmp+acc)+res. MODE 2: same but
// store into padb at (h+1,w+1) with key (w+1)&7.
struct AggP {
  const __bf16 *A, *B;  // B = qkv + 128 (V columns)
  __bf16* C;
  const __bf16 *tmp, *res;
  const float* gma;
  long long bB1, bB2, sBr;
  long long cB1, cB2, sCr;
};

template <int MODE>
__global__ __launch_bounds__(256) void agg_k(AggP p) {
  __shared__ __attribute__((aligned(16))) __bf16 lA[128 * 64];
  __shared__ __attribute__((aligned(16))) __bf16 lB[128 * 64];
  const int t = threadIdx.x;
  const int z = blockIdx.x;
  const int z1 = z / 96, z2 = z % 96;
  const __bf16* A = p.A + (long long)z * (96 * 128);
  const __bf16* B = p.B + (long long)z1 * p.bB1 + (long long)z2 * p.bB2;
  const int n0 = blockIdx.z * 128;
  const int lane = t & 63, wave = t >> 6;
  const int wm = (wave >> 1) * 64, wn = (wave & 1) * 64;
  const int l15 = lane & 15, l4 = lane >> 4;
  const int srow = lane >> 3, schunk = (lane & 7) * 8;
  f32x4 acc[4][4];
#pragma unroll
  for (int i = 0; i < 4; i++)
#pragma unroll
    for (int j = 0; j < 4; j++) acc[i][j] = f32x4{0.f, 0.f, 0.f, 0.f};

#pragma unroll
  for (int kb = 0; kb < 128; kb += 64) {
    const int rb = wave * 32;
#pragma unroll
    for (int i = 0; i < 4; i++) {
      int row = rb + i * 8;
      gload16(A + (long long)(row + srow) * 128 + kb + schunk, &lA[row * 64]);
    }
#pragma unroll
    for (int i = 0; i < 4; i++) {
      int slot = t + i * 256;
      int kl = slot & 63, cch = slot >> 6;
      int gk = kb + kl;
      I4B8 u;
      u.i = make_int4(0, 0, 0, 0);
      if (gk < 96) u.i = *(const int4*)(B + (long long)gk * p.sBr + n0 + cch * 8);
#pragma unroll
      for (int j = 0; j < 8; j++) {
        int n = cch * 8 + j;
        lB[n * 64 + (rot8(kl >> 3, n & 7) << 3) + (kl & 7)] = u.b[j];
      }
    }
    __syncthreads();
#pragma unroll
    for (int kk = 0; kk < 2; kk++) {
      bf8_t af[4], bfr[4];
      int cch = kk * 4 + l4;
#pragma unroll
      for (int mt = 0; mt < 4; mt++) {
        int r = wm + mt * 16 + l15;
        af[mt] = *(bf8_t*)&lA[r * 64 + (rot8(cch, r & 7) << 3)];
      }
#pragma unroll
      for (int nt = 0; nt < 4; nt++) {
        int r = wn + nt * 16 + l15;
        bfr[nt] = *(bf8_t*)&lB[r * 64 + (rot8(cch, r & 7) << 3)];
      }
#pragma unroll
      for (int mt = 0; mt < 4; mt++)
#pragma unroll
        for (int nt = 0; nt < 4; nt++)
          acc[mt][nt] = __builtin_amdgcn_mfma_f32_16x16x32_bf16(af[mt], bfr[nt], acc[mt][nt], 0, 0, 0);
    }
    __syncthreads();
  }
  long long cbase = (long long)z1 * p.cB1 + (long long)z2 * p.cB2;
  float g = MODE ? *p.gma : 0.f;
#pragma unroll
  for (int nt = 0; nt < 4; nt++) {
    int col = n0 + wn + nt * 16 + l15;
#pragma unroll
    for (int mt = 0; mt < 4; mt++) {
      int row0 = wm + mt * 16 + (l4 << 2);
#pragma unroll
      for (int r = 0; r < 4; r++) {
        int row = row0 + r;
        if (row >= 96) continue;
        long long offL = cbase + (long long)row * p.sCr + col;
        float v = acc[mt][nt][r];
        if (MODE == 0) {
          p.C[offL] = (__bf16)v;
        } else {
          int rc = (col & ~63) + (rot8((col >> 3) & 7, row & 7) << 3) + (col & 7);
          long long offP = cbase + (long long)row * p.sCr + rc;
          v = g * ((float)p.tmp[offL] + v) + (float)p.res[offP];
          if (MODE == 1) {
            p.C[offP] = (__bf16)v;
          } else {
            int pc = (col & ~63) + (rot8((col >> 3) & 7, (row + 1) & 7) << 3) + (col & 7);
            long long pidx = (long long)z1 * 9604 + (long long)(z2 + 1) * 98 + (row + 1);
            p.C[pidx * 512 + pc] = (__bf16)v;
          }
        }
      }
    }
  }
}

// ---------------------------------------------------------------- scores
// mode 0 (b,w): E[h][i] (diag -inf) -> attnfH[b*96+w][h*96+i]
// mode 1 (b,h): E[w][j]             -> attnfW[b*96+h][w*96+j]
__global__ __launch_bounds__(384) void cc_scores_k(const __bf16* qkv, float* attnfH, float* attnfW) {
  __shared__ __attribute__((aligned(16))) __bf16 Qs[96 * 64];
  __shared__ __attribute__((aligned(16))) __bf16 Ks[96 * 64];
  int bfi = blockIdx.x;
  int b = bfi / 96, f = bfi % 96;
  int mode = blockIdx.y;
  long long base = (mode == 0) ? ((long long)(b * 9216 + f)) * 640 : ((long long)(b * 9216 + f * 96)) * 640;
  long long rstr = (mode == 0) ? 96 * 640 : 640;
  int t = threadIdx.x;
#pragma unroll
  for (int i = 0; i < 2; i++) {
    int slot = t + i * 384;
    int r = slot >> 3, c = slot & 7;
    int sw = rot8(c, r & 7) << 3;
    *(int4*)&Qs[r * 64 + sw] = *(const int4*)(qkv + base + (long long)r * rstr + c * 8);
    *(int4*)&Ks[r * 64 + sw] = *(const int4*)(qkv + base + (long long)r * rstr + 64 + c * 8);
  }
  __syncthreads();
  int lane = t & 63, wave = t >> 6;
  int l15 = lane & 15, l4 = lane >> 4;
  f32x4 acc[6];
#pragma unroll
  for (int i = 0; i < 6; i++) acc[i] = f32x4{0.f, 0.f, 0.f, 0.f};
#pragma unroll
  for (int kk = 0; kk < 2; kk++) {
    int ar = wave * 16 + l15;
    int cch = kk * 4 + l4;
    bf8_t af = *(bf8_t*)&Qs[ar * 64 + (rot8(cch, ar & 7) << 3)];
#pragma unroll
    for (int nt = 0; nt < 6; nt++) {
      int br = nt * 16 + l15;
      bf8_t bfr = *(bf8_t*)&Ks[br * 64 + (rot8(cch, br & 7) << 3)];
      acc[nt] = __builtin_amdgcn_mfma_f32_16x16x32_bf16(af, bfr, acc[nt], 0, 0, 0);
    }
  }
  float* dst = (mode == 0 ? attnfH : attnfW) + (long long)bfi * 9216;
#pragma unroll
  for (int nt = 0; nt < 6; nt++) {
#pragma unroll
    for (int r = 0; r < 4; r++) {
      int m = wave * 16 + (l4 << 2) + r;
      int n = nt * 16 + l15;
      float v = acc[nt][r];
      if (mode == 0 && n == m) v = -__builtin_inff();
      dst[m * 96 + n] = v;
    }
  }
}

// softmax over concat[e_h, e_w] (192), writes padded+rotated a_h/a_w rows.
__global__ __launch_bounds__(256) void cc_softmax_k(const float* attnfH, const float* attnfW,
                                                    __bf16* a_h, __bf16* a_w) {
  int wave = threadIdx.x >> 6, lane = threadIdx.x & 63;
  int pix = blockIdx.x * 4 + wave;
  int b = pix / 9216, hw = pix % 9216;
  int h = hw / 96, w2 = hw % 96;
  const float* ehb = attnfH + ((long long)(b * 96 + w2)) * 9216 + h * 96;
  const float* ewb = attnfW + ((long long)(b * 96 + h)) * 9216 + w2 * 96;
  float x0 = ehb[lane];
  float x1 = lane < 32 ? ehb[64 + lane] : -__builtin_inff();
  float x2 = ewb[lane];
  float x3 = lane < 32 ? ewb[64 + lane] : -__builtin_inff();
  float m = fmaxf(fmaxf(x0, x1), fmaxf(x2, x3));
#pragma unroll
  for (int o = 32; o; o >>= 1) m = fmaxf(m, __shfl_xor(m, o));
  float e0 = __expf(x0 - m), e1 = __expf(x1 - m), e2 = __expf(x2 - m), e3 = __expf(x3 - m);
  float s = e0 + e1 + e2 + e3;
#pragma unroll
  for (int o = 32; o; o >>= 1) s += __shfl_xor(s, o);
  float inv = 1.f / s;
  // a_h row (h), key h&7 ; a_w row (w2), key w2&7
  __bf16* dh = a_h + ((long long)((b * 96 + w2) * 96 + h)) * 128;
  __bf16* dw = a_w + ((long long)((b * 96 + h) * 96 + w2)) * 128;
  int kh = h & 7, kw2 = w2 & 7;
  int k1 = lane, k2 = 64 + lane;
  int p1h = (k1 & ~63) + (rot8((k1 >> 3) & 7, kh) << 3) + (k1 & 7);
  int p2h = (k2 & ~63) + (rot8((k2 >> 3) & 7, kh) << 3) + (k2 & 7);
  int p1w = (k1 & ~63) + (rot8((k1 >> 3) & 7, kw2) << 3) + (k1 & 7);
  int p2w = (k2 & ~63) + (rot8((k2 >> 3) & 7, kw2) << 3) + (k2 & 7);
  dh[p1h] = (__bf16)(e0 * inv);
  dh[p2h] = (__bf16)(lane < 32 ? e1 * inv : 0.f);
  dw[p1w] = (__bf16)(e2 * inv);
  dw[p2w] = (__bf16)(lane < 32 ? e3 * inv : 0.f);
}

// ---------------------------------------------------------------- conv3x3
// R12: 96(M)x128(N) tiles, grid 768 (192m x 4n) = exactly 3 blocks/CU.
// 4 waves in 2x2, wave tile 48x64, acc[3][4]. LDS 28KB. Single-buffered
// 2-barrier K-loop (proven structure).
// R14: GN stats fused into epilogue (f32 partials -> shfl reduce -> LDS
// cross-wave -> 16 atomicAdd/block into stats[2*(b*32+g)]).
__global__ __launch_bounds__(256) void conv3_gemm_k(const __bf16* pin, const __bf16* wr, __bf16* C,
                                                    float* stats) {
  __shared__ __attribute__((aligned(16))) __bf16 lA[96 * 64];
  __shared__ __attribute__((aligned(16))) __bf16 lB[128 * 64];
  __shared__ float redS[4][4], redSS[4][4];
  const int t = threadIdx.x;
  const int id = blockIdx.x;
  const int per8 = gridDim.x >> 3;                 // 96
  const int lin = (id & 7) * per8 + (id >> 3);
  const int m0 = (lin >> 2) * 96, n0 = (lin & 3) * 128;
  const int lane = t & 63, wave = t >> 6;
  const int wm = (wave >> 1) * 48, wn = (wave & 1) * 64;
  const int l15 = lane & 15, l4 = lane >> 4;
  const int srow = lane >> 3, schunk = (lane & 7) * 8;
  const int rbA = wave * 24, rbB = wave * 32;
  f32x4 acc[3][4];
#pragma unroll
  for (int i = 0; i < 3; i++)
#pragma unroll
    for (int j = 0; j < 4; j++) acc[i][j] = f32x4{0.f, 0.f, 0.f, 0.f};
  long long sbase[3], bbase[4];
#pragma unroll
  for (int i = 0; i < 3; i++) {
    int r = rbA + i * 8 + srow;
    int m = m0 + r;
    int b = m / 9216, hw = m % 9216;
    int h = hw / 96, w2 = hw % 96;
    sbase[i] = ((long long)b * 9604 + h * 98 + w2) * 512 + schunk;
  }
#pragma unroll
  for (int i = 0; i < 4; i++) {
    int r = rbB + i * 8 + srow;
    bbase[i] = (long long)(n0 + r) * 4608 + schunk;
  }
  int w2f[3];
#pragma unroll
  for (int mt = 0; mt < 3; mt++) w2f[mt] = (m0 + wm + mt * 16 + l15) % 96;

  int kt = 0;
  for (int tap = 0; tap < 9; tap++) {
    const int dy = tap / 3, dx = tap - dy * 3;
    const long long aoff = (long long)(dy * 98 + dx) * 512;
    int keyA[3];
#pragma unroll
    for (int mt = 0; mt < 3; mt++) keyA[mt] = (w2f[mt] + dx) & 7;
    for (int sl = 0; sl < 8; sl++, kt++) {
      const int c0k = sl * 64;
#pragma unroll
      for (int i = 0; i < 3; i++)
        gload16(pin + sbase[i] + aoff + c0k, &lA[(rbA + i * 8) * 64]);
#pragma unroll
      for (int i = 0; i < 4; i++)
        gload16(wr + bbase[i] + kt * 64, &lB[(rbB + i * 8) * 64]);
      __syncthreads();
#pragma unroll
      for (int kk = 0; kk < 2; kk++) {
        bf8_t af[3], bfr[4];
        int cch = kk * 4 + l4;
#pragma unroll
        for (int mt = 0; mt < 3; mt++) {
          int r = wm + mt * 16 + l15;
          af[mt] = *(bf8_t*)&lA[r * 64 + (rot8(cch, keyA[mt]) << 3)];
        }
#pragma unroll
        for (int nt = 0; nt < 4; nt++) {
          int r = wn + nt * 16 + l15;
          bfr[nt] = *(bf8_t*)&lB[r * 64 + (rot8(cch, r & 7) << 3)];
        }
#pragma unroll
        for (int mt = 0; mt < 3; mt++)
#pragma unroll
          for (int nt = 0; nt < 4; nt++)
            acc[mt][nt] = __builtin_amdgcn_mfma_f32_16x16x32_bf16(af[mt], bfr[nt], acc[mt][nt], 0, 0, 0);
      }
      __syncthreads();
    }
  }
  float s4[4], ss4[4];
#pragma unroll
  for (int nt = 0; nt < 4; nt++) {
    float s = 0.f, ss = 0.f;
    int col = n0 + wn + nt * 16 + l15;
#pragma unroll
    for (int mt = 0; mt < 3; mt++) {
      int row0 = m0 + wm + mt * 16 + (l4 << 2);
#pragma unroll
      for (int r = 0; r < 4; r++) {
        int row = row0 + r;
        float v = acc[mt][nt][r];
        C[(long long)row * 512 + col] = (__bf16)v;
        s += v;
        ss += v * v;
      }
    }
    s4[nt] = s;
    ss4[nt] = ss;
  }
  // GN partials: wave-reduce, cross-wave combine, atomics.
#pragma unroll
  for (int nt = 0; nt < 4; nt++) {
#pragma unroll
    for (int o = 32; o; o >>= 1) {
      s4[nt] += __shfl_xor(s4[nt], o);
      ss4[nt] += __shfl_xor(ss4[nt], o);
    }
  }
  if (lane == 0) {
#pragma unroll
    for (int nt = 0; nt < 4; nt++) {
      redS[wave][nt] = s4[nt];
      redSS[wave][nt] = ss4[nt];
    }
  }
  __syncthreads();
  if (t < 8) {
    int nt = t & 3, half = t >> 2;         // half 0: wn=0 (waves 0,2); half 1: wn=64 (waves 1,3)
    float S = redS[half][nt] + redS[half + 2][nt];
    float SS = redSS[half][nt] + redSS[half + 2][nt];
    int b = m0 / 9216;
    int g = (n0 >> 4) + half * 4 + nt;
    atomicAdd(&stats[2 * (b * 32 + g)], S);
    atomicAdd(&stats[2 * (b * 32 + g) + 1], SS);
  }
}

// ---------------------------------------------------------------- GroupNorm
__global__ __launch_bounds__(256) void gn_write_k(const __bf16* z, const float* stats,
                                                 const float* gng, const float* gnb, float* out) {
  __shared__ __bf16 l[64 * 98];
  int c0 = blockIdx.x * 64, h = blockIdx.y, b = blockIdx.z;
  int t = threadIdx.x;
#pragma unroll
  for (int i = 0; i < 3; i++) {
    int slot = t + i * 256;
    int wl = slot >> 3, cch = slot & 7;
    I4B8 u;
    u.i = *(const int4*)(z + ((long long)(b * 9216 + h * 96 + wl)) * 512 + c0 + cch * 8);
#pragma unroll
    for (int j = 0; j < 8; j++) l[(cch * 8 + j) * 98 + wl] = u.b[j];
  }
  __syncthreads();
  const float inv = 1.f / 147456.f;
#pragma unroll
  for (int i = 0; i < 3; i++) {
    int slot = t + i * 256;
    int wch = slot % 12, cl = slot / 12;
    int c = c0 + cl;
    int g = c >> 4;
    float S = stats[2 * (b * 32 + g)], SS = stats[2 * (b * 32 + g) + 1];
    float mean = S * inv;
    float rstd = rsqrtf(SS * inv - mean * mean + 1e-5f);
    float sc = rstd * gng[c];
    float sh = gnb[c] - mean * sc;
    float4 o0, o1;
    const __bf16* src = &l[cl * 98 + wch * 8];
    o0.x = (float)src[0] * sc + sh; o0.y = (float)src[1] * sc + sh;
    o0.z = (float)src[2] * sc + sh; o0.w = (float)src[3] * sc + sh;
    o1.x = (float)src[4] * sc + sh; o1.y = (float)src[5] * sc + sh;
    o1.z = (float)src[6] * sc + sh; o1.w = (float)src[7] * sc + sh;
    float* dst = out + ((long long)((b * 512 + c) * 96 + h)) * 96 + wch * 8;
    *(float4*)dst = o0;
    *(float4*)(dst + 4) = o1;
  }
}

// ---------------------------------------------------------------- launch
extern "C" void kernel_launch(void* const* d_in, const int* in_sizes, int n_in,
                              void* d_out, int out_size, void* d_ws, size_t ws_size,
                              hipStream_t stream) {
  (void)in_sizes; (void)n_in; (void)out_size;
  const float* x = (const float*)d_in[0];
  const float* conv1w = (const float*)d_in[1];
  const float* conv1b = (const float*)d_in[2];
  const float* qw = (const float*)d_in[3];
  const float* qbias = (const float*)d_in[4];
  const float* kw = (const float*)d_in[5];
  const float* kbias = (const float*)d_in[6];
  const float* vw = (const float*)d_in[7];
  const float* vbias = (const float*)d_in[8];
  const float* gma = (const float*)d_in[9];
  const float* cow = (const float*)d_in[10];
  const float* gng = (const float*)d_in[11];
  const float* gnb = (const float*)d_in[12];
  float* out = (float*)d_out;

  if (ws_size < 134876160ULL) return;

  char* w = (char*)d_ws;
  __bf16* xt     = (__bf16*)(w);                 // 75,497,472 (phase 1)
  __bf16* qkv    = (__bf16*)(w);                 // 23,592,960
  float* attnfH  = (float*)(w + 23592960);       // 7,077,888
  float* attnfW  = (float*)(w + 30670848);       // 7,077,888
  __bf16* a_h    = (__bf16*)(w + 37748736);      // 4,718,592
  __bf16* a_w    = (__bf16*)(w + 42467328);      // 4,718,592
  __bf16* padb   = (__bf16*)(w + 47185920);      // 19,668,992
  __bf16* wrot   = (__bf16*)(w + 66854912);      // 4,718,592
  __bf16* ya     = (__bf16*)(w + 75497472);      // 18,874,368
  __bf16* yb     = (__bf16*)(w + 94371840);      // 18,874,368
  __bf16* tmp1   = (__bf16*)(w + 113246208);     // 18,874,368
  __bf16* zb     = (__bf16*)(w);                 // 18,874,368 (after attention)
  __bf16* c1wb   = (__bf16*)(w + 132120576);     // 2,097,152
  __bf16* wqkvb  = (__bf16*)(w + 134217728);     // 655,360
  float* qkvbias = (float*)(w + 134873088);      // 2,560
  float* stats   = (float*)(w + 134875648);      // 512

  cast_rot_k<<<512, 256, 0, stream>>>(conv1w, c1wb, 256, 131072);
  wqkv_rot_k<<<160, 256, 0, stream>>>(qw, kw, vw, wqkvb);
  fuse_bias_k<<<3, 256, 0, stream>>>(qbias, kbias, vbias, qkvbias, stats);
  transpose_x_k<<<dim3(32, 144, 2), 256, 0, stream>>>(x, xt);

  {  // conv1: ya = xt @ c1wb^T + b (rotated out). 192 m-tiles x 4 n-tiles.
    GemmAP p{};
    p.A = xt; p.B = c1wb; p.C = ya; p.bias = conv1b;
    p.sAr = 2048; p.sBr = 2048; p.sCr = 512;
    p.K = 2048; p.ntn = 4;
    gemm_async_k<1, 4><<<768, 256, 0, stream>>>(p);
  }

  for (int it = 0; it < 2; it++) {
    __bf16* tin = it ? yb : ya;
    {  // fused qkv projection. 192 m-tiles x 4 n-tiles (160-wide).
      GemmAP p{};
      p.A = tin; p.B = wqkvb; p.C = qkv; p.bias = qkvbias;
      p.sAr = 512; p.sBr = 512; p.sCr = 640;
      p.K = 512; p.ntn = 4;
      gemm_async_k<0, 5><<<768, 256, 0, stream>>>(p);
    }
    cc_scores_k<<<dim3(192, 2), 384, 0, stream>>>(qkv, attnfH, attnfW);
    cc_softmax_k<<<4608, 256, 0, stream>>>(attnfH, attnfW, a_h, a_w);
    {  // agg1: per (b,w): tmp1[b][h][w][c] = sum_i a_h[h,i] * v[b,i,w,c]
      AggP p{};
      p.A = a_h; p.B = qkv + 128; p.C = tmp1;
      p.bB1 = (long long)9216 * 640; p.bB2 = 640; p.sBr = (long long)96 * 640;
      p.cB1 = (long long)9216 * 512; p.cB2 = 512; p.sCr = (long long)96 * 512;
      agg_k<0><<<dim3(192, 1, 4), 256, 0, stream>>>(p);
    }
    {  // agg2 + epilogue: per (b,h)
      AggP p{};
      p.A = a_w; p.B = qkv + 128;
      p.bB1 = (long long)9216 * 640; p.bB2 = (long long)96 * 640; p.sBr = 640;
      p.cB1 = (long long)9216 * 512; p.cB2 = (long long)96 * 512; p.sCr = 512;
      p.tmp = tmp1; p.res = tin; p.gma = gma;
      if (it == 0) {
        p.C = yb;
        agg_k<1><<<dim3(192, 1, 4), 256, 0, stream>>>(p);
      } else {
        p.C = padb;
        agg_k<2><<<dim3(192, 1, 4), 256, 0, stream>>>(p);
      }
    }
  }

  reorder_w_k<<<512, 256, 0, stream>>>(cow, wrot);
  border0_k<<<194, 256, 0, stream>>>(padb);
  conv3_gemm_k<<<768, 256, 0, stream>>>(padb, wrot, zb, stats);
  gn_write_k<<<dim3(8, 96, 2), 256, 0, stream>>>(zb, stats, gng, gnb, out);
}